// Round 9
// baseline (452.127 us; speedup 1.0000x reference)
//
#include <hip/hip_runtime.h>
#include <math.h>

#define NEG_SLOPE 0.2f

typedef __attribute__((ext_vector_type(8))) short bf16x8;
typedef __attribute__((ext_vector_type(4))) float f32x4;
typedef __attribute__((ext_vector_type(2))) float f32x2;
typedef unsigned short u16;
typedef __attribute__((ext_vector_type(4))) unsigned short u16x4;

__device__ __forceinline__ float b2f(u16 u) {
    return __uint_as_float(((unsigned)u) << 16);
}
__device__ __forceinline__ u16 f2b(float f) {
    unsigned u = __float_as_uint(f);
    unsigned r = (u + 0x7fffu + ((u >> 16) & 1u)) >> 16;
    return (u16)r;
}

// ---------------- fused prep: cast x, transpose W1/W2, zero scratch --------
__global__ void prep(const float* __restrict__ x, u16* __restrict__ x_bf, int n4,
                     const float* __restrict__ W1, u16* __restrict__ w1t,
                     const float* __restrict__ W2, u16* __restrict__ w2t,
                     int* __restrict__ zero_base, int nzero,
                     int B0, int B1, int B2) {
    int blk = blockIdx.x;
    if (blk < B0) {
        int i = blk * 256 + threadIdx.x;
        if (i < n4) {
            float4 v = *reinterpret_cast<const float4*>(&x[i * 4]);
            u16x4 o;
            o[0] = f2b(v.x); o[1] = f2b(v.y); o[2] = f2b(v.z); o[3] = f2b(v.w);
            *reinterpret_cast<u16x4*>(&x_bf[i * 4]) = o;
        }
    } else if (blk < B1) {
        int i = (blk - B0) * 256 + threadIdx.x;  // [M][K], K=128, M=256
        if (i < 128 * 256) {
            int m = i >> 7, k = i & 127;
            w1t[i] = f2b(W1[(size_t)k * 256 + m]);
        }
    } else if (blk < B2) {
        int i = (blk - B1) * 256 + threadIdx.x;  // K=256, M=256
        if (i < 256 * 256) {
            int m = i >> 8, k = i & 255;
            w2t[i] = f2b(W2[(size_t)k * 256 + m]);
        }
    } else {
        int i = (blk - B2) * 256 + threadIdx.x;
        if (i < nzero) zero_base[i] = 0;
    }
}

// ---------------- MFMA GEMM: C[N,M] bf16 = A[N,K] bf16 * Bt[M,K]^T ----------
__global__ __launch_bounds__(256) void gemm_mfma(
        const u16* __restrict__ A, const u16* __restrict__ Bt,
        u16* __restrict__ C, int N, int K, int M) {
    __shared__ u16 As[128 * 64];
    __shared__ u16 Bs[128 * 64];
    const int tid = threadIdx.x;
    const int lane = tid & 63;
    const int wid = tid >> 6;
    const int wr = wid >> 1, wc = wid & 1;
    const int row0 = blockIdx.x * 128;
    const int col0 = blockIdx.y * 128;
    f32x4 acc[4][4] = {};
    for (int k0 = 0; k0 < K; k0 += 64) {
        if (k0) __syncthreads();
#pragma unroll
        for (int i = 0; i < 4; ++i) {
            int chunk = i * 256 + tid;
            int row = chunk >> 3;
            int slot = chunk & 7;
            int grow = row0 + row; if (grow >= N) grow = N - 1;
            bf16x8 v = *reinterpret_cast<const bf16x8*>(&A[(size_t)grow * K + k0 + slot * 8]);
            int swz = (chunk & ~7) | (slot ^ (row & 7));
            *reinterpret_cast<bf16x8*>(&As[swz * 8]) = v;
        }
#pragma unroll
        for (int i = 0; i < 4; ++i) {
            int chunk = i * 256 + tid;
            int row = chunk >> 3;
            int slot = chunk & 7;
            int gcol = col0 + row;
            bf16x8 v = *reinterpret_cast<const bf16x8*>(&Bt[(size_t)gcol * K + k0 + slot * 8]);
            int swz = (chunk & ~7) | (slot ^ (row & 7));
            *reinterpret_cast<bf16x8*>(&Bs[swz * 8]) = v;
        }
        __syncthreads();
#pragma unroll
        for (int kk = 0; kk < 2; ++kk) {
            bf16x8 ax[4], bx[4];
#pragma unroll
            for (int m = 0; m < 4; ++m) {
                int row = wr * 64 + m * 16 + (lane & 15);
                int slot = kk * 4 + (lane >> 4);
                ax[m] = *reinterpret_cast<const bf16x8*>(&As[(row * 8 + (slot ^ (row & 7))) * 8]);
            }
#pragma unroll
            for (int n = 0; n < 4; ++n) {
                int row = wc * 64 + n * 16 + (lane & 15);
                int slot = kk * 4 + (lane >> 4);
                bx[n] = *reinterpret_cast<const bf16x8*>(&Bs[(row * 8 + (slot ^ (row & 7))) * 8]);
            }
#pragma unroll
            for (int m = 0; m < 4; ++m)
#pragma unroll
                for (int n = 0; n < 4; ++n)
                    acc[m][n] = __builtin_amdgcn_mfma_f32_16x16x32_bf16(
                        ax[m], bx[n], acc[m][n], 0, 0, 0);
        }
    }
    const int crow = row0 + wr * 64;
    const int ccol = col0 + wc * 64;
#pragma unroll
    for (int m = 0; m < 4; ++m)
#pragma unroll
        for (int n = 0; n < 4; ++n)
#pragma unroll
            for (int r = 0; r < 4; ++r) {
                int rg = crow + m * 16 + (lane >> 4) * 4 + r;
                int cg = ccol + n * 16 + (lane & 15);
                if (rg < N) C[(size_t)rg * M + cg] = f2b(acc[m][n][r]);
            }
}

// ------- per-node: attn-dot exps (pa,qa), al_d, fp8 re-encode of h ---------
// pq layout: [n][head] float2 = (exp(al_s), exp(0.2*al_s))
__global__ void compute_al_cast(const u16* __restrict__ h, const float* __restrict__ a_s,
                                const float* __restrict__ a_d, int N,
                                float* __restrict__ pq, float* __restrict__ al_d,
                                unsigned* __restrict__ h8) {
    int i = blockIdx.x * blockDim.x + threadIdx.x;   // n*4 + head
    if (i < N * 4) {
        int hh = i & 3;
        const u16* hp = h + (size_t)(i >> 2) * 256 + hh * 64;
        const float* as = a_s + hh * 64;
        const float* ad = a_d + hh * 64;
        unsigned* op = h8 + (size_t)(i >> 2) * 64 + hh * 16;
        float ss = 0.f, sd = 0.f;
#pragma unroll
        for (int c0 = 0; c0 < 64; c0 += 8) {
            bf16x8 v = *reinterpret_cast<const bf16x8*>(&hp[c0]);
            float f[8];
#pragma unroll
            for (int j = 0; j < 8; ++j) {
                f[j] = b2f((u16)v[j]);
                ss = fmaf(f[j], as[c0 + j], ss);
                sd = fmaf(f[j], ad[c0 + j], sd);
            }
            int w0 = 0, w1 = 0;
            w0 = __builtin_amdgcn_cvt_pk_fp8_f32(f[0], f[1], w0, false);
            w0 = __builtin_amdgcn_cvt_pk_fp8_f32(f[2], f[3], w0, true);
            w1 = __builtin_amdgcn_cvt_pk_fp8_f32(f[4], f[5], w1, false);
            w1 = __builtin_amdgcn_cvt_pk_fp8_f32(f[6], f[7], w1, true);
            op[c0 / 4]     = (unsigned)w0;
            op[c0 / 4 + 1] = (unsigned)w1;
        }
        f32x2 pv;
        pv.x = expf(ss);
        pv.y = expf(NEG_SLOPE * ss);
        *reinterpret_cast<f32x2*>(&pq[(size_t)i * 2]) = pv;
        al_d[i] = sd;
    }
}

// ---------------- CSR build ----------------
__global__ void deg_hist(const int* __restrict__ dstI, int E, int Etot,
                         int* __restrict__ cnt) {
    int e = blockIdx.x * blockDim.x + threadIdx.x;
    if (e < Etot) {
        int d = (e < E) ? dstI[e] : (e - E);
        atomicAdd(&cnt[d], 1);
    }
}

// single-block exclusive scan, 4 elements/thread (writes rp AND cursor)
__global__ __launch_bounds__(1024) void scan_excl4(const int* __restrict__ cnt,
                                                   int* __restrict__ rp,
                                                   int* __restrict__ cursor, int N) {
    __shared__ int wsum[16];
    __shared__ int carry_s;
    int lane = threadIdx.x & 63;
    int wid = threadIdx.x >> 6;
    if (threadIdx.x == 0) carry_s = 0;
    __syncthreads();
    for (int base = 0; base < N; base += 4096) {
        int idx = base + (int)threadIdx.x * 4;
        int a0 = 0, a1 = 0, a2 = 0, a3 = 0;
        if (idx + 3 < N) {
            int4 v = *reinterpret_cast<const int4*>(&cnt[idx]);
            a0 = v.x; a1 = v.y; a2 = v.z; a3 = v.w;
        } else {
            if (idx < N)     a0 = cnt[idx];
            if (idx + 1 < N) a1 = cnt[idx + 1];
            if (idx + 2 < N) a2 = cnt[idx + 2];
        }
        int p1 = a0 + a1, p2 = p1 + a2, p3 = p2 + a3;
        int x = p3;
#pragma unroll
        for (int ofs = 1; ofs < 64; ofs <<= 1) {
            int t = __shfl_up(x, ofs, 64);
            if (lane >= ofs) x += t;
        }
        if (lane == 63) wsum[wid] = x;
        __syncthreads();
        if (wid == 0) {
            int y = (lane < 16) ? wsum[lane] : 0;
#pragma unroll
            for (int ofs = 1; ofs < 16; ofs <<= 1) {
                int t = __shfl_up(y, ofs, 64);
                if (lane >= ofs) y += t;
            }
            if (lane < 16) wsum[lane] = y;
        }
        __syncthreads();
        int wofs = (wid > 0) ? wsum[wid - 1] : 0;
        int carry = carry_s;
        int excl = carry + wofs + (x - p3);
        if (idx < N)     { rp[idx] = excl;          cursor[idx] = excl; }
        if (idx + 1 < N) { rp[idx + 1] = excl + a0; cursor[idx + 1] = excl + a0; }
        if (idx + 2 < N) { rp[idx + 2] = excl + p1; cursor[idx + 2] = excl + p1; }
        if (idx + 3 < N) { rp[idx + 3] = excl + p2; cursor[idx + 3] = excl + p2; }
        __syncthreads();
        if (threadIdx.x == 1023) carry_s = carry + wsum[15];
        __syncthreads();
    }
    if (threadIdx.x == 0) rp[N] = carry_s;
}

__global__ void csr_scatter(const int* __restrict__ srcI, const int* __restrict__ dstI,
                            int E, int Etot, int* __restrict__ cursor,
                            int* __restrict__ srcp) {
    int e = blockIdx.x * blockDim.x + threadIdx.x;
    if (e < Etot) {
        int s, d;
        if (e < E) { s = srcI[e]; d = dstI[e]; }
        else       { s = e - E;   d = e - E; }
        int pos = atomicAdd(&cursor[d], 1);
        srcp[pos] = s;
    }
}

// -------- single-pass fused aggregate (fp8 gather + exp-product), H=4 -------
template<bool ELU>
__global__ __launch_bounds__(256) void gat_fused_h4(
        const unsigned* __restrict__ h8, const float* __restrict__ pq,
        const float* __restrict__ al_d, const float* __restrict__ b,
        const int* __restrict__ rp, const int* __restrict__ srcp,
        int N, u16* __restrict__ out) {
    const int lane = threadIdx.x & 63;
    const int head = lane >> 4;
    int w = (blockIdx.x * blockDim.x + threadIdx.x) >> 6;
    int nw = (gridDim.x * blockDim.x) >> 6;
    for (int d = w; d < N; d += nw) {
        int i = rp[d], end = rp[d + 1];
        float ald = al_d[d * 4 + head];
        float pb = __expf(ald);
        float qb = __expf(NEG_SLOPE * ald);
        float acc0 = 0.f, acc1 = 0.f, acc2 = 0.f, acc3 = 0.f, L = 0.f;

#define EDGE(S) {                                                              \
        unsigned hv = h8[(unsigned)(S) * 64u + (unsigned)lane];                \
        f32x2 pqv = *reinterpret_cast<const f32x2*>(                           \
            &pq[(unsigned)(S) * 8u + (unsigned)head * 2u]);                    \
        float t = pqv.x * pb;                                                  \
        float e = (t > 1.f) ? t : pqv.y * qb;                                  \
        L += e;                                                                \
        f32x2 lo = __builtin_amdgcn_cvt_pk_f32_fp8((int)hv, false);            \
        f32x2 hi = __builtin_amdgcn_cvt_pk_f32_fp8((int)hv, true);             \
        acc0 = fmaf(e, lo.x, acc0); acc1 = fmaf(e, lo.y, acc1);                \
        acc2 = fmaf(e, hi.x, acc2); acc3 = fmaf(e, hi.y, acc3); }

        // prologue: align to 16B for int4 srcp loads
        for (; i < end && (i & 3); ++i) EDGE(srcp[i]);
        for (; i + 4 <= end; i += 4) {
            int4 s4 = *reinterpret_cast<const int4*>(&srcp[i]);
            EDGE(s4.x); EDGE(s4.y); EDGE(s4.z); EDGE(s4.w);
        }
        for (; i < end; ++i) EDGE(srcp[i]);
#undef EDGE

        float inv = 1.f / (L + 1e-16f);
        float4 bb = *reinterpret_cast<const float4*>(&b[lane * 4]);
        float o0 = fmaf(acc0, inv, bb.x);
        float o1 = fmaf(acc1, inv, bb.y);
        float o2 = fmaf(acc2, inv, bb.z);
        float o3 = fmaf(acc3, inv, bb.w);
        if (ELU) {
            o0 = (o0 > 0.f) ? o0 : expm1f(o0);
            o1 = (o1 > 0.f) ? o1 : expm1f(o1);
            o2 = (o2 > 0.f) ? o2 : expm1f(o2);
            o3 = (o3 > 0.f) ? o3 : expm1f(o3);
        }
        u16x4 ov;
        ov[0] = f2b(o0); ov[1] = f2b(o1); ov[2] = f2b(o2); ov[3] = f2b(o3);
        *reinterpret_cast<u16x4*>(&out[(size_t)d * 256 + lane * 4]) = ov;
    }
}

// ================= layer-3 linear-collapse path =============================
// pq3[n] = (exp(al_s), exp(0.2 al_s)); al_d[n] = dst dot
__global__ __launch_bounds__(256) void compute_al3(
        const u16* __restrict__ ob, const float* __restrict__ W3,
        const float* __restrict__ as3, const float* __restrict__ ad3, int N,
        float* __restrict__ pq3, float* __restrict__ al_d) {
    __shared__ float was[256], wad[256];
    {
        int t = threadIdx.x;
        float ss = 0.f, sd = 0.f;
#pragma unroll
        for (int c = 0; c < 10; ++c) {
            float w = W3[t * 10 + c];
            ss = fmaf(w, as3[c], ss);
            sd = fmaf(w, ad3[c], sd);
        }
        was[t] = ss; wad[t] = sd;
    }
    __syncthreads();
    const int lane = threadIdx.x & 63;
    int n = (blockIdx.x * blockDim.x + threadIdx.x) >> 6;
    if (n >= N) return;
    u16x4 hv = *reinterpret_cast<const u16x4*>(&ob[(size_t)n * 256 + lane * 4]);
    float4 ws = *reinterpret_cast<const float4*>(&was[lane * 4]);
    float4 wd = *reinterpret_cast<const float4*>(&wad[lane * 4]);
    float f0 = b2f((u16)hv[0]), f1 = b2f((u16)hv[1]);
    float f2 = b2f((u16)hv[2]), f3 = b2f((u16)hv[3]);
    float ss = f0 * ws.x + f1 * ws.y + f2 * ws.z + f3 * ws.w;
    float sd = f0 * wd.x + f1 * wd.y + f2 * wd.z + f3 * wd.w;
#pragma unroll
    for (int m = 1; m < 64; m <<= 1) {
        ss += __shfl_xor(ss, m, 64);
        sd += __shfl_xor(sd, m, 64);
    }
    if (lane == 0) {
        f32x2 pv; pv.x = expf(ss); pv.y = expf(NEG_SLOPE * ss);
        *reinterpret_cast<f32x2*>(&pq3[(size_t)n * 2]) = pv;
        al_d[n] = sd;
    }
}

// wave per destination: L in-wave, then scatter exp/L to sources
__global__ __launch_bounds__(256) void l3_edge(
        const float* __restrict__ pq3, const float* __restrict__ al_d,
        const int* __restrict__ rp, const int* __restrict__ srcp,
        int N, float* __restrict__ wq) {
    const int lane = threadIdx.x & 63;
    int w = (blockIdx.x * blockDim.x + threadIdx.x) >> 6;
    int nw = (gridDim.x * blockDim.x) >> 6;
    for (int d = w; d < N; d += nw) {
        int start = rp[d], end = rp[d + 1];
        float ald = al_d[d];
        float pb = __expf(ald);
        float qb = __expf(NEG_SLOPE * ald);
        float L = 0.f;
        for (int i = start + lane; i < end; i += 64) {
            f32x2 pqv = *reinterpret_cast<const f32x2*>(&pq3[(unsigned)srcp[i] * 2u]);
            float t = pqv.x * pb;
            L += (t > 1.f) ? t : pqv.y * qb;
        }
#pragma unroll
        for (int m = 1; m < 64; m <<= 1) L += __shfl_xor(L, m, 64);
        float inv = 1.f / (L + 1e-16f);
        for (int i = start + lane; i < end; i += 64) {
            int s = srcp[i];
            f32x2 pqv = *reinterpret_cast<const f32x2*>(&pq3[(unsigned)s * 2u]);
            float t = pqv.x * pb;
            float e = (t > 1.f) ? t : pqv.y * qb;
            atomicAdd(&wq[s], e * inv);
        }
    }
}

// pp[256] += w-weighted column sum of ob; LDS-reduced per block, then atomics
__global__ __launch_bounds__(256) void wcolsum(const u16* __restrict__ ob,
                                               const float* __restrict__ w, int N,
                                               float* __restrict__ pp) {
    __shared__ float sh[4][256];
    const int lane = threadIdx.x & 63;
    const int wid = threadIdx.x >> 6;
    int wv = (blockIdx.x * blockDim.x + threadIdx.x) >> 6;
    int nw = (gridDim.x * blockDim.x) >> 6;
    float a0 = 0.f, a1 = 0.f, a2 = 0.f, a3 = 0.f;
    for (int n = wv; n < N; n += nw) {
        float wn = w[n];
        u16x4 hv = *reinterpret_cast<const u16x4*>(&ob[(size_t)n * 256 + lane * 4]);
        a0 = fmaf(wn, b2f((u16)hv[0]), a0);
        a1 = fmaf(wn, b2f((u16)hv[1]), a1);
        a2 = fmaf(wn, b2f((u16)hv[2]), a2);
        a3 = fmaf(wn, b2f((u16)hv[3]), a3);
    }
    sh[wid][lane * 4 + 0] = a0;
    sh[wid][lane * 4 + 1] = a1;
    sh[wid][lane * 4 + 2] = a2;
    sh[wid][lane * 4 + 3] = a3;
    __syncthreads();
    int t = threadIdx.x;
    float s = sh[0][t] + sh[1][t] + sh[2][t] + sh[3][t];
    atomicAdd(&pp[t], s);
}

// out = log_softmax(pp/N @ W3 + b3)
__global__ void final_out(const float* __restrict__ pp, const float* __restrict__ W3,
                          const float* __restrict__ b3, int N, float* __restrict__ out) {
    __shared__ float acc[10];
    int t = threadIdx.x;  // 256
    if (t < 10) acc[t] = 0.f;
    __syncthreads();
    float pk = pp[t] / (float)N;
#pragma unroll
    for (int c = 0; c < 10; ++c) atomicAdd(&acc[c], pk * W3[t * 10 + c]);
    __syncthreads();
    if (t == 0) {
        float p[10];
        float mx = -INFINITY;
        for (int c = 0; c < 10; ++c) {
            p[c] = acc[c] + b3[c];
            mx = fmaxf(mx, p[c]);
        }
        float s = 0.f;
        for (int c = 0; c < 10; ++c) s += expf(p[c] - mx);
        float ls = logf(s);
        for (int c = 0; c < 10; ++c) out[c] = p[c] - mx - ls;
    }
}

extern "C" void kernel_launch(void* const* d_in, const int* in_sizes, int n_in,
                              void* d_out, int out_size, void* d_ws, size_t ws_size,
                              hipStream_t stream) {
    const float* x   = (const float*)d_in[0];
    const int*   ei  = (const int*)d_in[1];
    const float* W1  = (const float*)d_in[2];
    const float* as1 = (const float*)d_in[3];
    const float* ad1 = (const float*)d_in[4];
    const float* b1  = (const float*)d_in[5];
    const float* W2  = (const float*)d_in[6];
    const float* as2 = (const float*)d_in[7];
    const float* ad2 = (const float*)d_in[8];
    const float* b2  = (const float*)d_in[9];
    const float* W3  = (const float*)d_in[10];
    const float* as3 = (const float*)d_in[11];
    const float* ad3 = (const float*)d_in[12];
    const float* b3  = (const float*)d_in[13];
    float* out = (float*)d_out;

    const int N = in_sizes[0] / 128;   // 50000
    const int E = in_sizes[1] / 2;     // 800000
    const int Etot = E + N;
    const int* srcI = ei;
    const int* dstI = ei + E;

    char* base = (char*)d_ws;
    size_t off = 0;
    auto alloc = [&](size_t bytes) {
        void* p = base + off;
        off = (off + bytes + 255) & ~(size_t)255;
        return p;
    };
    u16* x_bf  = (u16*)alloc((size_t)N * 128 * 2);
    u16* h_bf  = (u16*)alloc((size_t)N * 256 * 2);
    unsigned* h8 = (unsigned*)alloc((size_t)N * 256);
    u16* oa_bf = (u16*)alloc((size_t)N * 256 * 2);
    u16* ob_bf = (u16*)alloc((size_t)N * 256 * 2);
    u16* w1t   = (u16*)alloc(256 * 128 * 2);
    u16* w2t   = (u16*)alloc(256 * 256 * 2);
    float* pq   = (float*)alloc((size_t)N * 8 * 4);   // [n][4] float2
    float* al_d = (float*)alloc((size_t)N * 4 * 4);
    float* pq3  = (float*)alloc((size_t)N * 2 * 4);   // [n] float2
    // contiguous zero region: cnt | wq | pp
    int* cnt    = (int*)alloc((size_t)N * 4);
    float* wq   = (float*)alloc((size_t)N * 4);
    float* pp   = (float*)alloc(256 * 4);
    int* rp     = (int*)alloc((size_t)(N + 1) * 4);
    int* cursor = (int*)alloc((size_t)N * 4);
    int* srcp   = (int*)alloc((size_t)Etot * 4);

    // ---- prep: cast x, transpose weights, zero scratch (one dispatch) ----
    const int n4 = N * 128 / 4;
    const int B0 = (n4 + 255) / 256;
    const int B1 = B0 + (128 * 256 + 255) / 256;
    const int B2 = B1 + (256 * 256 + 255) / 256;
    int span = (int)(((char*)(pp + 256) - (char*)cnt) / 4);
    const int B3 = B2 + (span + 255) / 256;
    prep<<<B3, 256, 0, stream>>>(x, x_bf, n4, W1, w1t, W2, w2t,
                                 cnt, span, B0, B1, B2);

    deg_hist<<<(Etot + 255) / 256, 256, 0, stream>>>(dstI, E, Etot, cnt);
    scan_excl4<<<1, 1024, 0, stream>>>(cnt, rp, cursor, N);
    csr_scatter<<<(Etot + 255) / 256, 256, 0, stream>>>(srcI, dstI, E, Etot, cursor, srcp);

    const int FUSED_BLOCKS = (N + 3) / 4;
    const int GX = (N + 127) / 128;

    // ---- layer 1: x_bf[N,128] -> oa_bf[N,256], ELU ----
    {
        dim3 g(GX, 2);
        gemm_mfma<<<g, 256, 0, stream>>>(x_bf, w1t, h_bf, N, 128, 256);
        compute_al_cast<<<(N * 4 + 255) / 256, 256, 0, stream>>>(h_bf, as1, ad1, N,
                                                                 pq, al_d, h8);
        gat_fused_h4<true><<<FUSED_BLOCKS, 256, 0, stream>>>(
            h8, pq, al_d, b1, rp, srcp, N, oa_bf);
    }
    // ---- layer 2: oa_bf -> ob_bf, ELU ----
    {
        dim3 g(GX, 2);
        gemm_mfma<<<g, 256, 0, stream>>>(oa_bf, w2t, h_bf, N, 256, 256);
        compute_al_cast<<<(N * 4 + 255) / 256, 256, 0, stream>>>(h_bf, as2, ad2, N,
                                                                 pq, al_d, h8);
        gat_fused_h4<true><<<FUSED_BLOCKS, 256, 0, stream>>>(
            h8, pq, al_d, b2, rp, srcp, N, ob_bf);
    }
    // ---- layer 3 (linear-collapsed): pooled = (1/N * sum_s w_s ob_s) @ W3 + b3
    {
        compute_al3<<<(N + 3) / 4, 256, 0, stream>>>(ob_bf, W3, as3, ad3, N, pq3, al_d);
        l3_edge<<<(N + 3) / 4, 256, 0, stream>>>(pq3, al_d, rp, srcp, N, wq);
        wcolsum<<<1024, 256, 0, stream>>>(ob_bf, wq, N, pp);
        final_out<<<1, 256, 0, stream>>>(pp, W3, b3, N, out);
    }
}

// Round 10
// 410.872 us; speedup vs baseline: 1.1004x; 1.1004x over previous
//
#include <hip/hip_runtime.h>
#include <math.h>

#define NEG_SLOPE 0.2f

typedef __attribute__((ext_vector_type(8))) short bf16x8;
typedef __attribute__((ext_vector_type(4))) float f32x4;
typedef __attribute__((ext_vector_type(2))) float f32x2;
typedef unsigned short u16;
typedef __attribute__((ext_vector_type(4))) unsigned short u16x4;

__device__ __forceinline__ float b2f(u16 u) {
    return __uint_as_float(((unsigned)u) << 16);
}
__device__ __forceinline__ u16 f2b(float f) {
    unsigned u = __float_as_uint(f);
    unsigned r = (u + 0x7fffu + ((u >> 16) & 1u)) >> 16;
    return (u16)r;
}

// ---------------- fused prep: cast x, transpose W1/W2, zero scratch --------
__global__ void prep(const float* __restrict__ x, u16* __restrict__ x_bf, int n4,
                     const float* __restrict__ W1, u16* __restrict__ w1t,
                     const float* __restrict__ W2, u16* __restrict__ w2t,
                     int* __restrict__ zero_base, int nzero,
                     int B0, int B1, int B2) {
    int blk = blockIdx.x;
    if (blk < B0) {
        int i = blk * 256 + threadIdx.x;
        if (i < n4) {
            float4 v = *reinterpret_cast<const float4*>(&x[i * 4]);
            u16x4 o;
            o[0] = f2b(v.x); o[1] = f2b(v.y); o[2] = f2b(v.z); o[3] = f2b(v.w);
            *reinterpret_cast<u16x4*>(&x_bf[i * 4]) = o;
        }
    } else if (blk < B1) {
        int i = (blk - B0) * 256 + threadIdx.x;  // [M][K], K=128, M=256
        if (i < 128 * 256) {
            int m = i >> 7, k = i & 127;
            w1t[i] = f2b(W1[(size_t)k * 256 + m]);
        }
    } else if (blk < B2) {
        int i = (blk - B1) * 256 + threadIdx.x;  // K=256, M=256
        if (i < 256 * 256) {
            int m = i >> 8, k = i & 255;
            w2t[i] = f2b(W2[(size_t)k * 256 + m]);
        }
    } else {
        int i = (blk - B2) * 256 + threadIdx.x;
        if (i < nzero) zero_base[i] = 0;
    }
}

// ---------------- MFMA GEMM: C[N,M] bf16 = A[N,K] bf16 * Bt[M,K]^T ----------
__global__ __launch_bounds__(256) void gemm_mfma(
        const u16* __restrict__ A, const u16* __restrict__ Bt,
        u16* __restrict__ C, int N, int K, int M) {
    __shared__ u16 As[128 * 64];
    __shared__ u16 Bs[128 * 64];
    const int tid = threadIdx.x;
    const int lane = tid & 63;
    const int wid = tid >> 6;
    const int wr = wid >> 1, wc = wid & 1;
    const int row0 = blockIdx.x * 128;
    const int col0 = blockIdx.y * 128;
    f32x4 acc[4][4] = {};
    for (int k0 = 0; k0 < K; k0 += 64) {
        if (k0) __syncthreads();
#pragma unroll
        for (int i = 0; i < 4; ++i) {
            int chunk = i * 256 + tid;
            int row = chunk >> 3;
            int slot = chunk & 7;
            int grow = row0 + row; if (grow >= N) grow = N - 1;
            bf16x8 v = *reinterpret_cast<const bf16x8*>(&A[(size_t)grow * K + k0 + slot * 8]);
            int swz = (chunk & ~7) | (slot ^ (row & 7));
            *reinterpret_cast<bf16x8*>(&As[swz * 8]) = v;
        }
#pragma unroll
        for (int i = 0; i < 4; ++i) {
            int chunk = i * 256 + tid;
            int row = chunk >> 3;
            int slot = chunk & 7;
            int gcol = col0 + row;
            bf16x8 v = *reinterpret_cast<const bf16x8*>(&Bt[(size_t)gcol * K + k0 + slot * 8]);
            int swz = (chunk & ~7) | (slot ^ (row & 7));
            *reinterpret_cast<bf16x8*>(&Bs[swz * 8]) = v;
        }
        __syncthreads();
#pragma unroll
        for (int kk = 0; kk < 2; ++kk) {
            bf16x8 ax[4], bx[4];
#pragma unroll
            for (int m = 0; m < 4; ++m) {
                int row = wr * 64 + m * 16 + (lane & 15);
                int slot = kk * 4 + (lane >> 4);
                ax[m] = *reinterpret_cast<const bf16x8*>(&As[(row * 8 + (slot ^ (row & 7))) * 8]);
            }
#pragma unroll
            for (int n = 0; n < 4; ++n) {
                int row = wc * 64 + n * 16 + (lane & 15);
                int slot = kk * 4 + (lane >> 4);
                bx[n] = *reinterpret_cast<const bf16x8*>(&Bs[(row * 8 + (slot ^ (row & 7))) * 8]);
            }
#pragma unroll
            for (int m = 0; m < 4; ++m)
#pragma unroll
                for (int n = 0; n < 4; ++n)
                    acc[m][n] = __builtin_amdgcn_mfma_f32_16x16x32_bf16(
                        ax[m], bx[n], acc[m][n], 0, 0, 0);
        }
    }
    const int crow = row0 + wr * 64;
    const int ccol = col0 + wc * 64;
#pragma unroll
    for (int m = 0; m < 4; ++m)
#pragma unroll
        for (int n = 0; n < 4; ++n)
#pragma unroll
            for (int r = 0; r < 4; ++r) {
                int rg = crow + m * 16 + (lane >> 4) * 4 + r;
                int cg = ccol + n * 16 + (lane & 15);
                if (rg < N) C[(size_t)rg * M + cg] = f2b(acc[m][n][r]);
            }
}

// ------- per-node attn dots + fp8 re-encode, coalesced: 2 nodes per wave ----
// lane layout: half = lane>>5 selects node, l32 = lane&31 covers 8 channels
__global__ __launch_bounds__(256) void compute_al_cast(
        const u16* __restrict__ h, const float* __restrict__ a_s,
        const float* __restrict__ a_d, int N,
        float* __restrict__ pq, float* __restrict__ al_d,
        unsigned* __restrict__ h8) {
    const int lane = threadIdx.x & 63;
    const int half = lane >> 5;
    const int l32 = lane & 31;
    int w = (blockIdx.x * blockDim.x + threadIdx.x) >> 6;
    int n = w * 2 + half;
    if (n >= N) return;
    const int head = l32 >> 3;          // 0..3
    const int c0 = l32 * 8;             // channel base
    bf16x8 v = *reinterpret_cast<const bf16x8*>(&h[(size_t)n * 256 + c0]);
    const float* asf = a_s + head * 64 + (l32 & 7) * 8;
    const float* adf = a_d + head * 64 + (l32 & 7) * 8;
    float ss = 0.f, sd = 0.f;
    float f[8];
#pragma unroll
    for (int j = 0; j < 8; ++j) {
        f[j] = b2f((u16)v[j]);
        ss = fmaf(f[j], asf[j], ss);
        sd = fmaf(f[j], adf[j], sd);
    }
    int w0 = 0, w1 = 0;
    w0 = __builtin_amdgcn_cvt_pk_fp8_f32(f[0], f[1], w0, false);
    w0 = __builtin_amdgcn_cvt_pk_fp8_f32(f[2], f[3], w0, true);
    w1 = __builtin_amdgcn_cvt_pk_fp8_f32(f[4], f[5], w1, false);
    w1 = __builtin_amdgcn_cvt_pk_fp8_f32(f[6], f[7], w1, true);
    uint2 hw; hw.x = (unsigned)w0; hw.y = (unsigned)w1;
    *reinterpret_cast<uint2*>(&h8[(size_t)n * 64 + 2 * l32]) = hw;
#pragma unroll
    for (int m = 1; m < 8; m <<= 1) {
        ss += __shfl_xor(ss, m, 64);
        sd += __shfl_xor(sd, m, 64);
    }
    if ((l32 & 7) == 0) {
        f32x2 pv; pv.x = __expf(ss); pv.y = __expf(NEG_SLOPE * ss);
        *reinterpret_cast<f32x2*>(&pq[(size_t)n * 8 + head * 2]) = pv;
        al_d[n * 4 + head] = sd;
    }
}

// ---------------- CSR build ----------------
__global__ void deg_hist(const int* __restrict__ dstI, int E, int Etot,
                         int* __restrict__ cnt) {
    int e = blockIdx.x * blockDim.x + threadIdx.x;
    if (e < Etot) {
        int d = (e < E) ? dstI[e] : (e - E);
        atomicAdd(&cnt[d], 1);
    }
}

__global__ __launch_bounds__(1024) void scan_excl4(const int* __restrict__ cnt,
                                                   int* __restrict__ rp,
                                                   int* __restrict__ cursor, int N) {
    __shared__ int wsum[16];
    __shared__ int carry_s;
    int lane = threadIdx.x & 63;
    int wid = threadIdx.x >> 6;
    if (threadIdx.x == 0) carry_s = 0;
    __syncthreads();
    for (int base = 0; base < N; base += 4096) {
        int idx = base + (int)threadIdx.x * 4;
        int a0 = 0, a1 = 0, a2 = 0, a3 = 0;
        if (idx + 3 < N) {
            int4 v = *reinterpret_cast<const int4*>(&cnt[idx]);
            a0 = v.x; a1 = v.y; a2 = v.z; a3 = v.w;
        } else {
            if (idx < N)     a0 = cnt[idx];
            if (idx + 1 < N) a1 = cnt[idx + 1];
            if (idx + 2 < N) a2 = cnt[idx + 2];
        }
        int p1 = a0 + a1, p2 = p1 + a2, p3 = p2 + a3;
        int x = p3;
#pragma unroll
        for (int ofs = 1; ofs < 64; ofs <<= 1) {
            int t = __shfl_up(x, ofs, 64);
            if (lane >= ofs) x += t;
        }
        if (lane == 63) wsum[wid] = x;
        __syncthreads();
        if (wid == 0) {
            int y = (lane < 16) ? wsum[lane] : 0;
#pragma unroll
            for (int ofs = 1; ofs < 16; ofs <<= 1) {
                int t = __shfl_up(y, ofs, 64);
                if (lane >= ofs) y += t;
            }
            if (lane < 16) wsum[lane] = y;
        }
        __syncthreads();
        int wofs = (wid > 0) ? wsum[wid - 1] : 0;
        int carry = carry_s;
        int excl = carry + wofs + (x - p3);
        if (idx < N)     { rp[idx] = excl;          cursor[idx] = excl; }
        if (idx + 1 < N) { rp[idx + 1] = excl + a0; cursor[idx + 1] = excl + a0; }
        if (idx + 2 < N) { rp[idx + 2] = excl + p1; cursor[idx + 2] = excl + p1; }
        if (idx + 3 < N) { rp[idx + 3] = excl + p2; cursor[idx + 3] = excl + p2; }
        __syncthreads();
        if (threadIdx.x == 1023) carry_s = carry + wsum[15];
        __syncthreads();
    }
    if (threadIdx.x == 0) rp[N] = carry_s;
}

__global__ void csr_scatter(const int* __restrict__ srcI, const int* __restrict__ dstI,
                            int E, int Etot, int* __restrict__ cursor,
                            int* __restrict__ srcp) {
    int e = blockIdx.x * blockDim.x + threadIdx.x;
    if (e < Etot) {
        int s, d;
        if (e < E) { s = srcI[e]; d = dstI[e]; }
        else       { s = e - E;   d = e - E; }
        int pos = atomicAdd(&cursor[d], 1);
        srcp[pos] = s;
    }
}

// -------- single-pass fused aggregate (fp8 gather, depth-8 pipeline) --------
template<bool ELU>
__global__ __launch_bounds__(256) void gat_fused_h4(
        const unsigned* __restrict__ h8, const float* __restrict__ pq,
        const float* __restrict__ al_d, const float* __restrict__ b,
        const int* __restrict__ rp, const int* __restrict__ srcp,
        int N, u16* __restrict__ out) {
    const int lane = threadIdx.x & 63;
    const int head = lane >> 4;
    int w = (blockIdx.x * blockDim.x + threadIdx.x) >> 6;
    int nw = (gridDim.x * blockDim.x) >> 6;
    for (int d = w; d < N; d += nw) {
        int i = rp[d], end = rp[d + 1];
        float ald = al_d[d * 4 + head];
        float pb = __expf(ald);
        float qb = __expf(NEG_SLOPE * ald);
        float acc0 = 0.f, acc1 = 0.f, acc2 = 0.f, acc3 = 0.f, L = 0.f;

#define EDGE1(S) {                                                             \
        unsigned hv_ = h8[(unsigned)(S) * 64u + (unsigned)lane];               \
        f32x2 pv_ = *reinterpret_cast<const f32x2*>(                           \
            &pq[(unsigned)(S) * 8u + (unsigned)head * 2u]);                    \
        float t_ = pv_.x * pb;                                                 \
        float e_ = (t_ > 1.f) ? t_ : pv_.y * qb;                               \
        L += e_;                                                               \
        f32x2 lo_ = __builtin_amdgcn_cvt_pk_f32_fp8((int)hv_, false);          \
        f32x2 hi_ = __builtin_amdgcn_cvt_pk_f32_fp8((int)hv_, true);           \
        acc0 = fmaf(e_, lo_.x, acc0); acc1 = fmaf(e_, lo_.y, acc1);            \
        acc2 = fmaf(e_, hi_.x, acc2); acc3 = fmaf(e_, hi_.y, acc3); }

        // prologue: align to 16B for int4 srcp loads
        for (; i < end && (i & 3); ++i) EDGE1(srcp[i]);
        // depth-8 batches: issue all loads first, then compute
        for (; i + 8 <= end; i += 8) {
            int4 sa = *reinterpret_cast<const int4*>(&srcp[i]);
            int4 sb = *reinterpret_cast<const int4*>(&srcp[i + 4]);
            int ss[8] = {sa.x, sa.y, sa.z, sa.w, sb.x, sb.y, sb.z, sb.w};
            unsigned hv[8];
            f32x2 pv[8];
#pragma unroll
            for (int j = 0; j < 8; ++j) {
                hv[j] = h8[(unsigned)ss[j] * 64u + (unsigned)lane];
                pv[j] = *reinterpret_cast<const f32x2*>(
                    &pq[(unsigned)ss[j] * 8u + (unsigned)head * 2u]);
            }
#pragma unroll
            for (int j = 0; j < 8; ++j) {
                float t = pv[j].x * pb;
                float e = (t > 1.f) ? t : pv[j].y * qb;
                L += e;
                f32x2 lo = __builtin_amdgcn_cvt_pk_f32_fp8((int)hv[j], false);
                f32x2 hi = __builtin_amdgcn_cvt_pk_f32_fp8((int)hv[j], true);
                acc0 = fmaf(e, lo.x, acc0); acc1 = fmaf(e, lo.y, acc1);
                acc2 = fmaf(e, hi.x, acc2); acc3 = fmaf(e, hi.y, acc3);
            }
        }
        if (i + 4 <= end) {
            int4 sa = *reinterpret_cast<const int4*>(&srcp[i]);
            int ss[4] = {sa.x, sa.y, sa.z, sa.w};
            unsigned hv[4];
            f32x2 pv[4];
#pragma unroll
            for (int j = 0; j < 4; ++j) {
                hv[j] = h8[(unsigned)ss[j] * 64u + (unsigned)lane];
                pv[j] = *reinterpret_cast<const f32x2*>(
                    &pq[(unsigned)ss[j] * 8u + (unsigned)head * 2u]);
            }
#pragma unroll
            for (int j = 0; j < 4; ++j) {
                float t = pv[j].x * pb;
                float e = (t > 1.f) ? t : pv[j].y * qb;
                L += e;
                f32x2 lo = __builtin_amdgcn_cvt_pk_f32_fp8((int)hv[j], false);
                f32x2 hi = __builtin_amdgcn_cvt_pk_f32_fp8((int)hv[j], true);
                acc0 = fmaf(e, lo.x, acc0); acc1 = fmaf(e, lo.y, acc1);
                acc2 = fmaf(e, hi.x, acc2); acc3 = fmaf(e, hi.y, acc3);
            }
            i += 4;
        }
        for (; i < end; ++i) EDGE1(srcp[i]);
#undef EDGE1

        float inv = 1.f / (L + 1e-16f);
        float4 bb = *reinterpret_cast<const float4*>(&b[lane * 4]);
        float o0 = fmaf(acc0, inv, bb.x);
        float o1 = fmaf(acc1, inv, bb.y);
        float o2 = fmaf(acc2, inv, bb.z);
        float o3 = fmaf(acc3, inv, bb.w);
        if (ELU) {
            o0 = (o0 > 0.f) ? o0 : expm1f(o0);
            o1 = (o1 > 0.f) ? o1 : expm1f(o1);
            o2 = (o2 > 0.f) ? o2 : expm1f(o2);
            o3 = (o3 > 0.f) ? o3 : expm1f(o3);
        }
        u16x4 ov;
        ov[0] = f2b(o0); ov[1] = f2b(o1); ov[2] = f2b(o2); ov[3] = f2b(o3);
        *reinterpret_cast<u16x4*>(&out[(size_t)d * 256 + lane * 4]) = ov;
    }
}

// ================= layer-3 linear-collapse path =============================
__global__ __launch_bounds__(256) void compute_al3(
        const u16* __restrict__ ob, const float* __restrict__ W3,
        const float* __restrict__ as3, const float* __restrict__ ad3, int N,
        float* __restrict__ pq3, float* __restrict__ al_d) {
    __shared__ float was[256], wad[256];
    {
        int t = threadIdx.x;
        float ss = 0.f, sd = 0.f;
#pragma unroll
        for (int c = 0; c < 10; ++c) {
            float w = W3[t * 10 + c];
            ss = fmaf(w, as3[c], ss);
            sd = fmaf(w, ad3[c], sd);
        }
        was[t] = ss; wad[t] = sd;
    }
    __syncthreads();
    const int lane = threadIdx.x & 63;
    int n = (blockIdx.x * blockDim.x + threadIdx.x) >> 6;
    if (n >= N) return;
    u16x4 hv = *reinterpret_cast<const u16x4*>(&ob[(size_t)n * 256 + lane * 4]);
    float4 ws = *reinterpret_cast<const float4*>(&was[lane * 4]);
    float4 wd = *reinterpret_cast<const float4*>(&wad[lane * 4]);
    float f0 = b2f((u16)hv[0]), f1 = b2f((u16)hv[1]);
    float f2 = b2f((u16)hv[2]), f3 = b2f((u16)hv[3]);
    float ss = f0 * ws.x + f1 * ws.y + f2 * ws.z + f3 * ws.w;
    float sd = f0 * wd.x + f1 * wd.y + f2 * wd.z + f3 * wd.w;
#pragma unroll
    for (int m = 1; m < 64; m <<= 1) {
        ss += __shfl_xor(ss, m, 64);
        sd += __shfl_xor(sd, m, 64);
    }
    if (lane == 0) {
        f32x2 pv; pv.x = __expf(ss); pv.y = __expf(NEG_SLOPE * ss);
        *reinterpret_cast<f32x2*>(&pq3[(size_t)n * 2]) = pv;
        al_d[n] = sd;
    }
}

__global__ __launch_bounds__(256) void l3_edge(
        const float* __restrict__ pq3, const float* __restrict__ al_d,
        const int* __restrict__ rp, const int* __restrict__ srcp,
        int N, float* __restrict__ wq) {
    const int lane = threadIdx.x & 63;
    int w = (blockIdx.x * blockDim.x + threadIdx.x) >> 6;
    int nw = (gridDim.x * blockDim.x) >> 6;
    for (int d = w; d < N; d += nw) {
        int start = rp[d], end = rp[d + 1];
        float ald = al_d[d];
        float pb = __expf(ald);
        float qb = __expf(NEG_SLOPE * ald);
        float L = 0.f;
        for (int i = start + lane; i < end; i += 64) {
            f32x2 pqv = *reinterpret_cast<const f32x2*>(&pq3[(unsigned)srcp[i] * 2u]);
            float t = pqv.x * pb;
            L += (t > 1.f) ? t : pqv.y * qb;
        }
#pragma unroll
        for (int m = 1; m < 64; m <<= 1) L += __shfl_xor(L, m, 64);
        float inv = 1.f / (L + 1e-16f);
        for (int i = start + lane; i < end; i += 64) {
            int s = srcp[i];
            f32x2 pqv = *reinterpret_cast<const f32x2*>(&pq3[(unsigned)s * 2u]);
            float t = pqv.x * pb;
            float e = (t > 1.f) ? t : pqv.y * qb;
            atomicAdd(&wq[s], e * inv);
        }
    }
}

__global__ __launch_bounds__(256) void wcolsum(const u16* __restrict__ ob,
                                               const float* __restrict__ w, int N,
                                               float* __restrict__ pp) {
    __shared__ float sh[4][256];
    const int lane = threadIdx.x & 63;
    const int wid = threadIdx.x >> 6;
    int wv = (blockIdx.x * blockDim.x + threadIdx.x) >> 6;
    int nw = (gridDim.x * blockDim.x) >> 6;
    float a0 = 0.f, a1 = 0.f, a2 = 0.f, a3 = 0.f;
    for (int n = wv; n < N; n += nw) {
        float wn = w[n];
        u16x4 hv = *reinterpret_cast<const u16x4*>(&ob[(size_t)n * 256 + lane * 4]);
        a0 = fmaf(wn, b2f((u16)hv[0]), a0);
        a1 = fmaf(wn, b2f((u16)hv[1]), a1);
        a2 = fmaf(wn, b2f((u16)hv[2]), a2);
        a3 = fmaf(wn, b2f((u16)hv[3]), a3);
    }
    sh[wid][lane * 4 + 0] = a0;
    sh[wid][lane * 4 + 1] = a1;
    sh[wid][lane * 4 + 2] = a2;
    sh[wid][lane * 4 + 3] = a3;
    __syncthreads();
    int t = threadIdx.x;
    float s = sh[0][t] + sh[1][t] + sh[2][t] + sh[3][t];
    atomicAdd(&pp[t], s);
}

__global__ void final_out(const float* __restrict__ pp, const float* __restrict__ W3,
                          const float* __restrict__ b3, int N, float* __restrict__ out) {
    __shared__ float acc[10];
    int t = threadIdx.x;  // 256
    if (t < 10) acc[t] = 0.f;
    __syncthreads();
    float pk = pp[t] / (float)N;
#pragma unroll
    for (int c = 0; c < 10; ++c) atomicAdd(&acc[c], pk * W3[t * 10 + c]);
    __syncthreads();
    if (t == 0) {
        float p[10];
        float mx = -INFINITY;
        for (int c = 0; c < 10; ++c) {
            p[c] = acc[c] + b3[c];
            mx = fmaxf(mx, p[c]);
        }
        float s = 0.f;
        for (int c = 0; c < 10; ++c) s += expf(p[c] - mx);
        float ls = logf(s);
        for (int c = 0; c < 10; ++c) out[c] = p[c] - mx - ls;
    }
}

extern "C" void kernel_launch(void* const* d_in, const int* in_sizes, int n_in,
                              void* d_out, int out_size, void* d_ws, size_t ws_size,
                              hipStream_t stream) {
    const float* x   = (const float*)d_in[0];
    const int*   ei  = (const int*)d_in[1];
    const float* W1  = (const float*)d_in[2];
    const float* as1 = (const float*)d_in[3];
    const float* ad1 = (const float*)d_in[4];
    const float* b1  = (const float*)d_in[5];
    const float* W2  = (const float*)d_in[6];
    const float* as2 = (const float*)d_in[7];
    const float* ad2 = (const float*)d_in[8];
    const float* b2  = (const float*)d_in[9];
    const float* W3  = (const float*)d_in[10];
    const float* as3 = (const float*)d_in[11];
    const float* ad3 = (const float*)d_in[12];
    const float* b3  = (const float*)d_in[13];
    float* out = (float*)d_out;

    const int N = in_sizes[0] / 128;   // 50000
    const int E = in_sizes[1] / 2;     // 800000
    const int Etot = E + N;
    const int* srcI = ei;
    const int* dstI = ei + E;

    char* base = (char*)d_ws;
    size_t off = 0;
    auto alloc = [&](size_t bytes) {
        void* p = base + off;
        off = (off + bytes + 255) & ~(size_t)255;
        return p;
    };
    u16* x_bf  = (u16*)alloc((size_t)N * 128 * 2);
    u16* h_bf  = (u16*)alloc((size_t)N * 256 * 2);
    unsigned* h8 = (unsigned*)alloc((size_t)N * 256);
    u16* oa_bf = (u16*)alloc((size_t)N * 256 * 2);
    u16* ob_bf = (u16*)alloc((size_t)N * 256 * 2);
    u16* w1t   = (u16*)alloc(256 * 128 * 2);
    u16* w2t   = (u16*)alloc(256 * 256 * 2);
    float* pq   = (float*)alloc((size_t)N * 8 * 4);   // [n][4] float2
    float* al_d = (float*)alloc((size_t)N * 4 * 4);
    float* pq3  = (float*)alloc((size_t)N * 2 * 4);   // [n] float2
    // contiguous zero region: cnt | wq | pp
    int* cnt    = (int*)alloc((size_t)N * 4);
    float* wq   = (float*)alloc((size_t)N * 4);
    float* pp   = (float*)alloc(256 * 4);
    int* rp     = (int*)alloc((size_t)(N + 1) * 4);
    int* cursor = (int*)alloc((size_t)N * 4);
    int* srcp   = (int*)alloc((size_t)Etot * 4);

    // ---- prep: cast x, transpose weights, zero scratch (one dispatch) ----
    const int n4 = N * 128 / 4;
    const int B0 = (n4 + 255) / 256;
    const int B1 = B0 + (128 * 256 + 255) / 256;
    const int B2 = B1 + (256 * 256 + 255) / 256;
    int span = (int)(((char*)(pp + 256) - (char*)cnt) / 4);
    const int B3 = B2 + (span + 255) / 256;
    prep<<<B3, 256, 0, stream>>>(x, x_bf, n4, W1, w1t, W2, w2t,
                                 cnt, span, B0, B1, B2);

    deg_hist<<<(Etot + 255) / 256, 256, 0, stream>>>(dstI, E, Etot, cnt);
    scan_excl4<<<1, 1024, 0, stream>>>(cnt, rp, cursor, N);
    csr_scatter<<<(Etot + 255) / 256, 256, 0, stream>>>(srcI, dstI, E, Etot, cursor, srcp);

    const int FUSED_BLOCKS = (N + 3) / 4;
    const int ALC_BLOCKS = (N / 2 + 3) / 4;   // 2 nodes per wave, 4 waves/block
    const int GX = (N + 127) / 128;

    // ---- layer 1: x_bf[N,128] -> oa_bf[N,256], ELU ----
    {
        dim3 g(GX, 2);
        gemm_mfma<<<g, 256, 0, stream>>>(x_bf, w1t, h_bf, N, 128, 256);
        compute_al_cast<<<ALC_BLOCKS, 256, 0, stream>>>(h_bf, as1, ad1, N,
                                                        pq, al_d, h8);
        gat_fused_h4<true><<<FUSED_BLOCKS, 256, 0, stream>>>(
            h8, pq, al_d, b1, rp, srcp, N, oa_bf);
    }
    // ---- layer 2: oa_bf -> ob_bf, ELU ----
    {
        dim3 g(GX, 2);
        gemm_mfma<<<g, 256, 0, stream>>>(oa_bf, w2t, h_bf, N, 256, 256);
        compute_al_cast<<<ALC_BLOCKS, 256, 0, stream>>>(h_bf, as2, ad2, N,
                                                        pq, al_d, h8);
        gat_fused_h4<true><<<FUSED_BLOCKS, 256, 0, stream>>>(
            h8, pq, al_d, b2, rp, srcp, N, ob_bf);
    }
    // ---- layer 3 (linear-collapsed): pooled = (1/N * sum_s w_s ob_s) @ W3 + b3
    {
        compute_al3<<<(N + 3) / 4, 256, 0, stream>>>(ob_bf, W3, as3, ad3, N, pq3, al_d);
        l3_edge<<<(N + 3) / 4, 256, 0, stream>>>(pq3, al_d, rp, srcp, N, wq);
        wcolsum<<<1024, 256, 0, stream>>>(ob_bf, wq, N, pp);
        final_out<<<1, 256, 0, stream>>>(pp, W3, b3, N, out);
    }
}

// Round 11
// 331.621 us; speedup vs baseline: 1.3634x; 1.2390x over previous
//
#include <hip/hip_runtime.h>
#include <math.h>

#define NEG_SLOPE 0.2f

typedef __attribute__((ext_vector_type(8))) short bf16x8;
typedef __attribute__((ext_vector_type(4))) float f32x4;
typedef __attribute__((ext_vector_type(2))) float f32x2;
typedef unsigned short u16;
typedef __attribute__((ext_vector_type(4))) unsigned short u16x4;

__device__ __forceinline__ float b2f(u16 u) {
    return __uint_as_float(((unsigned)u) << 16);
}
__device__ __forceinline__ u16 f2b(float f) {
    unsigned u = __float_as_uint(f);
    unsigned r = (u + 0x7fffu + ((u >> 16) & 1u)) >> 16;
    return (u16)r;
}

// ---------------- fused prep: cast x, transpose W1/W2, zero scratch --------
__global__ void prep(const float* __restrict__ x, u16* __restrict__ x_bf, int n4,
                     const float* __restrict__ W1, u16* __restrict__ w1t,
                     const float* __restrict__ W2, u16* __restrict__ w2t,
                     int* __restrict__ zero_base, int nzero,
                     int B0, int B1, int B2) {
    int blk = blockIdx.x;
    if (blk < B0) {
        int i = blk * 256 + threadIdx.x;
        if (i < n4) {
            float4 v = *reinterpret_cast<const float4*>(&x[i * 4]);
            u16x4 o;
            o[0] = f2b(v.x); o[1] = f2b(v.y); o[2] = f2b(v.z); o[3] = f2b(v.w);
            *reinterpret_cast<u16x4*>(&x_bf[i * 4]) = o;
        }
    } else if (blk < B1) {
        int i = (blk - B0) * 256 + threadIdx.x;  // [M][K], K=128, M=256
        if (i < 128 * 256) {
            int m = i >> 7, k = i & 127;
            w1t[i] = f2b(W1[(size_t)k * 256 + m]);
        }
    } else if (blk < B2) {
        int i = (blk - B1) * 256 + threadIdx.x;  // K=256, M=256
        if (i < 256 * 256) {
            int m = i >> 8, k = i & 255;
            w2t[i] = f2b(W2[(size_t)k * 256 + m]);
        }
    } else {
        int i = (blk - B2) * 256 + threadIdx.x;
        if (i < nzero) zero_base[i] = 0;
    }
}

// ---------------- MFMA GEMM: C[N,M] bf16 = A[N,K] bf16 * Bt[M,K]^T ----------
__global__ __launch_bounds__(256) void gemm_mfma(
        const u16* __restrict__ A, const u16* __restrict__ Bt,
        u16* __restrict__ C, int N, int K, int M) {
    __shared__ u16 As[128 * 64];
    __shared__ u16 Bs[128 * 64];
    const int tid = threadIdx.x;
    const int lane = tid & 63;
    const int wid = tid >> 6;
    const int wr = wid >> 1, wc = wid & 1;
    const int row0 = blockIdx.x * 128;
    const int col0 = blockIdx.y * 128;
    f32x4 acc[4][4] = {};
    for (int k0 = 0; k0 < K; k0 += 64) {
        if (k0) __syncthreads();
#pragma unroll
        for (int i = 0; i < 4; ++i) {
            int chunk = i * 256 + tid;
            int row = chunk >> 3;
            int slot = chunk & 7;
            int grow = row0 + row; if (grow >= N) grow = N - 1;
            bf16x8 v = *reinterpret_cast<const bf16x8*>(&A[(size_t)grow * K + k0 + slot * 8]);
            int swz = (chunk & ~7) | (slot ^ (row & 7));
            *reinterpret_cast<bf16x8*>(&As[swz * 8]) = v;
        }
#pragma unroll
        for (int i = 0; i < 4; ++i) {
            int chunk = i * 256 + tid;
            int row = chunk >> 3;
            int slot = chunk & 7;
            int gcol = col0 + row;
            bf16x8 v = *reinterpret_cast<const bf16x8*>(&Bt[(size_t)gcol * K + k0 + slot * 8]);
            int swz = (chunk & ~7) | (slot ^ (row & 7));
            *reinterpret_cast<bf16x8*>(&Bs[swz * 8]) = v;
        }
        __syncthreads();
#pragma unroll
        for (int kk = 0; kk < 2; ++kk) {
            bf16x8 ax[4], bx[4];
#pragma unroll
            for (int m = 0; m < 4; ++m) {
                int row = wr * 64 + m * 16 + (lane & 15);
                int slot = kk * 4 + (lane >> 4);
                ax[m] = *reinterpret_cast<const bf16x8*>(&As[(row * 8 + (slot ^ (row & 7))) * 8]);
            }
#pragma unroll
            for (int n = 0; n < 4; ++n) {
                int row = wc * 64 + n * 16 + (lane & 15);
                int slot = kk * 4 + (lane >> 4);
                bx[n] = *reinterpret_cast<const bf16x8*>(&Bs[(row * 8 + (slot ^ (row & 7))) * 8]);
            }
#pragma unroll
            for (int m = 0; m < 4; ++m)
#pragma unroll
                for (int n = 0; n < 4; ++n)
                    acc[m][n] = __builtin_amdgcn_mfma_f32_16x16x32_bf16(
                        ax[m], bx[n], acc[m][n], 0, 0, 0);
        }
    }
    const int crow = row0 + wr * 64;
    const int ccol = col0 + wc * 64;
#pragma unroll
    for (int m = 0; m < 4; ++m)
#pragma unroll
        for (int n = 0; n < 4; ++n)
#pragma unroll
            for (int r = 0; r < 4; ++r) {
                int rg = crow + m * 16 + (lane >> 4) * 4 + r;
                int cg = ccol + n * 16 + (lane & 15);
                if (rg < N) C[(size_t)rg * M + cg] = f2b(acc[m][n][r]);
            }
}

// ------- per-node attn dots + fp8 re-encode, coalesced: 2 nodes per wave ----
__global__ __launch_bounds__(256) void compute_al_cast(
        const u16* __restrict__ h, const float* __restrict__ a_s,
        const float* __restrict__ a_d, int N,
        float* __restrict__ pq, float* __restrict__ al_d,
        unsigned* __restrict__ h8) {
    const int lane = threadIdx.x & 63;
    const int half = lane >> 5;
    const int l32 = lane & 31;
    int w = (blockIdx.x * blockDim.x + threadIdx.x) >> 6;
    int n = w * 2 + half;
    if (n >= N) return;
    const int head = l32 >> 3;          // 0..3
    const int c0 = l32 * 8;             // channel base
    bf16x8 v = *reinterpret_cast<const bf16x8*>(&h[(size_t)n * 256 + c0]);
    const float* asf = a_s + head * 64 + (l32 & 7) * 8;
    const float* adf = a_d + head * 64 + (l32 & 7) * 8;
    float ss = 0.f, sd = 0.f;
    float f[8];
#pragma unroll
    for (int j = 0; j < 8; ++j) {
        f[j] = b2f((u16)v[j]);
        ss = fmaf(f[j], asf[j], ss);
        sd = fmaf(f[j], adf[j], sd);
    }
    int w0 = 0, w1 = 0;
    w0 = __builtin_amdgcn_cvt_pk_fp8_f32(f[0], f[1], w0, false);
    w0 = __builtin_amdgcn_cvt_pk_fp8_f32(f[2], f[3], w0, true);
    w1 = __builtin_amdgcn_cvt_pk_fp8_f32(f[4], f[5], w1, false);
    w1 = __builtin_amdgcn_cvt_pk_fp8_f32(f[6], f[7], w1, true);
    uint2 hw; hw.x = (unsigned)w0; hw.y = (unsigned)w1;
    *reinterpret_cast<uint2*>(&h8[(size_t)n * 64 + 2 * l32]) = hw;
#pragma unroll
    for (int m = 1; m < 8; m <<= 1) {
        ss += __shfl_xor(ss, m, 64);
        sd += __shfl_xor(sd, m, 64);
    }
    if ((l32 & 7) == 0) {
        f32x2 pv; pv.x = __expf(ss); pv.y = __expf(NEG_SLOPE * ss);
        *reinterpret_cast<f32x2*>(&pq[(size_t)n * 8 + head * 2]) = pv;
        al_d[n * 4 + head] = sd;
    }
}

// ================= bucketed CSR build (128-dst buckets) =====================
// Kernel A: bucket histogram (LDS-staged)
__global__ __launch_bounds__(256) void bucket_hist(
        const int* __restrict__ dstI, int E, int Etot,
        int* __restrict__ bcnt, int NB) {
    __shared__ int h[512];
    int t = threadIdx.x;
    for (int j = t; j < NB; j += 256) h[j] = 0;
    __syncthreads();
    int base = blockIdx.x * 2048;
#pragma unroll
    for (int j = 0; j < 8; ++j) {
        int e = base + j * 256 + t;
        if (e < Etot) {
            int d = (e < E) ? dstI[e] : (e - E);
            atomicAdd(&h[d >> 7], 1);
        }
    }
    __syncthreads();
    for (int j = t; j < NB; j += 256)
        if (h[j]) atomicAdd(&bcnt[j], h[j]);
}

// Kernel B: scan bucket counts -> bbase, bcursor; also rp[N]=Etot
__global__ __launch_bounds__(512) void bucket_scan(
        const int* __restrict__ bcnt, int NB, int Etot,
        int* __restrict__ bbase, int* __restrict__ bcursor,
        int* __restrict__ rp, int N) {
    __shared__ int a[512], b[512];
    int t = threadIdx.x;
    a[t] = (t < NB) ? bcnt[t] : 0;
    __syncthreads();
    int* s = a; int* d = b;
    for (int ofs = 1; ofs < 512; ofs <<= 1) {
        d[t] = (t >= ofs) ? s[t] + s[t - ofs] : s[t];
        __syncthreads();
        int* tmp = s; s = d; d = tmp;
    }
    int excl = (t == 0) ? 0 : s[t - 1];
    if (t < NB) { bbase[t] = excl; bcursor[t] = excl; }
    if (t == NB) bbase[NB] = Etot;
    if (t == 0) rp[N] = Etot;
}

// Kernel C: bin edges into buckets; record = (dlow7<<16)|src (src<65536)
#define EPB 16
__global__ __launch_bounds__(256) void bin_scatter(
        const int* __restrict__ srcI, const int* __restrict__ dstI,
        int E, int Etot, int* __restrict__ bcursor,
        unsigned* __restrict__ binned, int NB) {
    __shared__ int cnt[512];
    int t = threadIdx.x;
    for (int j = t; j < NB; j += 256) cnt[j] = 0;
    __syncthreads();
    int base_e = blockIdx.x * (256 * EPB) + t;
    unsigned rec[EPB];
    int bkt[EPB];
#pragma unroll
    for (int j = 0; j < EPB; ++j) {
        int e = base_e + j * 256;
        bkt[j] = -1;
        if (e < Etot) {
            int s = (e < E) ? srcI[e] : (e - E);
            int d = (e < E) ? dstI[e] : (e - E);
            bkt[j] = d >> 7;
            rec[j] = ((unsigned)(d & 127) << 16) | (unsigned)s;
            atomicAdd(&cnt[bkt[j]], 1);
        }
    }
    __syncthreads();
    for (int j = t; j < NB; j += 256) {
        int c = cnt[j];
        cnt[j] = c ? atomicAdd(&bcursor[j], c) : 0;
    }
    __syncthreads();
#pragma unroll
    for (int j = 0; j < EPB; ++j)
        if (bkt[j] >= 0) {
            int pos = atomicAdd(&cnt[bkt[j]], 1);
            binned[pos] = rec[j];
        }
}

// Kernel D: per-bucket: build rp slice + scatter src (u16) into CSR order
__global__ __launch_bounds__(256) void bucket_csr(
        const unsigned* __restrict__ binned, const int* __restrict__ bbase,
        int N, int* __restrict__ rp, u16* __restrict__ srcp) {
    int b = blockIdx.x;
    int start = bbase[b];
    int cnt = bbase[b + 1] - start;
    __shared__ int dcnt[128];
    __shared__ int dofs[128];
    __shared__ int wtot;
    int t = threadIdx.x;
    if (t < 128) dcnt[t] = 0;
    __syncthreads();
    for (int i = t; i < cnt; i += 256)
        atomicAdd(&dcnt[binned[start + i] >> 16], 1);
    __syncthreads();
    int v = 0, x = 0;
    if (t < 128) {
        v = dcnt[t];
        x = v;
#pragma unroll
        for (int ofs = 1; ofs < 64; ofs <<= 1) {
            int u = __shfl_up(x, ofs, 64);
            if ((t & 63) >= ofs) x += u;
        }
    }
    if (t == 63) wtot = x;
    __syncthreads();
    if (t >= 64 && t < 128) x += wtot;
    if (t < 128) {
        int abs0 = start + (x - v);
        int d = b * 128 + t;
        if (d < N) rp[d] = abs0;
        dofs[t] = abs0;
    }
    __syncthreads();
    for (int i = t; i < cnt; i += 256) {
        unsigned rec = binned[start + i];
        int pos = atomicAdd(&dofs[rec >> 16], 1);
        srcp[pos] = (u16)(rec & 0xFFFFu);
    }
}

// -------- single-pass fused aggregate (fp8 gather, depth-8 pipeline) --------
template<bool ELU>
__global__ __launch_bounds__(256) void gat_fused_h4(
        const unsigned* __restrict__ h8, const float* __restrict__ pq,
        const float* __restrict__ al_d, const float* __restrict__ b,
        const int* __restrict__ rp, const u16* __restrict__ srcp,
        int N, u16* __restrict__ out) {
    const int lane = threadIdx.x & 63;
    const int head = lane >> 4;
    int w = (blockIdx.x * blockDim.x + threadIdx.x) >> 6;
    int nw = (gridDim.x * blockDim.x) >> 6;
    for (int d = w; d < N; d += nw) {
        int i = rp[d], end = rp[d + 1];
        float ald = al_d[d * 4 + head];
        float pb = __expf(ald);
        float qb = __expf(NEG_SLOPE * ald);
        float acc0 = 0.f, acc1 = 0.f, acc2 = 0.f, acc3 = 0.f, L = 0.f;

#define EDGE1(S) {                                                             \
        unsigned hv_ = h8[(unsigned)(S) * 64u + (unsigned)lane];               \
        f32x2 pv_ = *reinterpret_cast<const f32x2*>(                           \
            &pq[(unsigned)(S) * 8u + (unsigned)head * 2u]);                    \
        float t_ = pv_.x * pb;                                                 \
        float e_ = (t_ > 1.f) ? t_ : pv_.y * qb;                               \
        L += e_;                                                               \
        f32x2 lo_ = __builtin_amdgcn_cvt_pk_f32_fp8((int)hv_, false);          \
        f32x2 hi_ = __builtin_amdgcn_cvt_pk_f32_fp8((int)hv_, true);           \
        acc0 = fmaf(e_, lo_.x, acc0); acc1 = fmaf(e_, lo_.y, acc1);            \
        acc2 = fmaf(e_, hi_.x, acc2); acc3 = fmaf(e_, hi_.y, acc3); }

        // prologue: align to 8B for u16x4 srcp loads
        for (; i < end && (i & 3); ++i) EDGE1(srcp[i]);
        // depth-8 batches: issue all loads first, then compute
        for (; i + 8 <= end; i += 8) {
            u16x4 sa = *reinterpret_cast<const u16x4*>(&srcp[i]);
            u16x4 sb = *reinterpret_cast<const u16x4*>(&srcp[i + 4]);
            unsigned ss[8] = {sa[0], sa[1], sa[2], sa[3], sb[0], sb[1], sb[2], sb[3]};
            unsigned hv[8];
            f32x2 pv[8];
#pragma unroll
            for (int j = 0; j < 8; ++j) {
                hv[j] = h8[ss[j] * 64u + (unsigned)lane];
                pv[j] = *reinterpret_cast<const f32x2*>(
                    &pq[ss[j] * 8u + (unsigned)head * 2u]);
            }
#pragma unroll
            for (int j = 0; j < 8; ++j) {
                float t = pv[j].x * pb;
                float e = (t > 1.f) ? t : pv[j].y * qb;
                L += e;
                f32x2 lo = __builtin_amdgcn_cvt_pk_f32_fp8((int)hv[j], false);
                f32x2 hi = __builtin_amdgcn_cvt_pk_f32_fp8((int)hv[j], true);
                acc0 = fmaf(e, lo.x, acc0); acc1 = fmaf(e, lo.y, acc1);
                acc2 = fmaf(e, hi.x, acc2); acc3 = fmaf(e, hi.y, acc3);
            }
        }
        if (i + 4 <= end) {
            u16x4 sa = *reinterpret_cast<const u16x4*>(&srcp[i]);
            unsigned ss[4] = {sa[0], sa[1], sa[2], sa[3]};
            unsigned hv[4];
            f32x2 pv[4];
#pragma unroll
            for (int j = 0; j < 4; ++j) {
                hv[j] = h8[ss[j] * 64u + (unsigned)lane];
                pv[j] = *reinterpret_cast<const f32x2*>(
                    &pq[ss[j] * 8u + (unsigned)head * 2u]);
            }
#pragma unroll
            for (int j = 0; j < 4; ++j) {
                float t = pv[j].x * pb;
                float e = (t > 1.f) ? t : pv[j].y * qb;
                L += e;
                f32x2 lo = __builtin_amdgcn_cvt_pk_f32_fp8((int)hv[j], false);
                f32x2 hi = __builtin_amdgcn_cvt_pk_f32_fp8((int)hv[j], true);
                acc0 = fmaf(e, lo.x, acc0); acc1 = fmaf(e, lo.y, acc1);
                acc2 = fmaf(e, hi.x, acc2); acc3 = fmaf(e, hi.y, acc3);
            }
            i += 4;
        }
        for (; i < end; ++i) EDGE1(srcp[i]);
#undef EDGE1

        float inv = 1.f / (L + 1e-16f);
        float4 bb = *reinterpret_cast<const float4*>(&b[lane * 4]);
        float o0 = fmaf(acc0, inv, bb.x);
        float o1 = fmaf(acc1, inv, bb.y);
        float o2 = fmaf(acc2, inv, bb.z);
        float o3 = fmaf(acc3, inv, bb.w);
        if (ELU) {
            o0 = (o0 > 0.f) ? o0 : expm1f(o0);
            o1 = (o1 > 0.f) ? o1 : expm1f(o1);
            o2 = (o2 > 0.f) ? o2 : expm1f(o2);
            o3 = (o3 > 0.f) ? o3 : expm1f(o3);
        }
        u16x4 ov;
        ov[0] = f2b(o0); ov[1] = f2b(o1); ov[2] = f2b(o2); ov[3] = f2b(o3);
        *reinterpret_cast<u16x4*>(&out[(size_t)d * 256 + lane * 4]) = ov;
    }
}

// ================= layer-3 linear-collapse path =============================
__global__ __launch_bounds__(256) void compute_al3(
        const u16* __restrict__ ob, const float* __restrict__ W3,
        const float* __restrict__ as3, const float* __restrict__ ad3, int N,
        float* __restrict__ pq3, float* __restrict__ al_d) {
    __shared__ float was[256], wad[256];
    {
        int t = threadIdx.x;
        float ss = 0.f, sd = 0.f;
#pragma unroll
        for (int c = 0; c < 10; ++c) {
            float w = W3[t * 10 + c];
            ss = fmaf(w, as3[c], ss);
            sd = fmaf(w, ad3[c], sd);
        }
        was[t] = ss; wad[t] = sd;
    }
    __syncthreads();
    const int lane = threadIdx.x & 63;
    int n = (blockIdx.x * blockDim.x + threadIdx.x) >> 6;
    if (n >= N) return;
    u16x4 hv = *reinterpret_cast<const u16x4*>(&ob[(size_t)n * 256 + lane * 4]);
    float4 ws = *reinterpret_cast<const float4*>(&was[lane * 4]);
    float4 wd = *reinterpret_cast<const float4*>(&wad[lane * 4]);
    float f0 = b2f((u16)hv[0]), f1 = b2f((u16)hv[1]);
    float f2 = b2f((u16)hv[2]), f3 = b2f((u16)hv[3]);
    float ss = f0 * ws.x + f1 * ws.y + f2 * ws.z + f3 * ws.w;
    float sd = f0 * wd.x + f1 * wd.y + f2 * wd.z + f3 * wd.w;
#pragma unroll
    for (int m = 1; m < 64; m <<= 1) {
        ss += __shfl_xor(ss, m, 64);
        sd += __shfl_xor(sd, m, 64);
    }
    if (lane == 0) {
        f32x2 pv; pv.x = __expf(ss); pv.y = __expf(NEG_SLOPE * ss);
        *reinterpret_cast<f32x2*>(&pq3[(size_t)n * 2]) = pv;
        al_d[n] = sd;
    }
}

__global__ __launch_bounds__(256) void l3_edge(
        const float* __restrict__ pq3, const float* __restrict__ al_d,
        const int* __restrict__ rp, const u16* __restrict__ srcp,
        int N, float* __restrict__ wq) {
    const int lane = threadIdx.x & 63;
    int w = (blockIdx.x * blockDim.x + threadIdx.x) >> 6;
    int nw = (gridDim.x * blockDim.x) >> 6;
    for (int d = w; d < N; d += nw) {
        int start = rp[d], end = rp[d + 1];
        float ald = al_d[d];
        float pb = __expf(ald);
        float qb = __expf(NEG_SLOPE * ald);
        float L = 0.f;
        for (int i = start + lane; i < end; i += 64) {
            f32x2 pqv = *reinterpret_cast<const f32x2*>(&pq3[(unsigned)srcp[i] * 2u]);
            float t = pqv.x * pb;
            L += (t > 1.f) ? t : pqv.y * qb;
        }
#pragma unroll
        for (int m = 1; m < 64; m <<= 1) L += __shfl_xor(L, m, 64);
        float inv = 1.f / (L + 1e-16f);
        for (int i = start + lane; i < end; i += 64) {
            unsigned s = srcp[i];
            f32x2 pqv = *reinterpret_cast<const f32x2*>(&pq3[s * 2u]);
            float t = pqv.x * pb;
            float e = (t > 1.f) ? t : pqv.y * qb;
            atomicAdd(&wq[s], e * inv);
        }
    }
}

__global__ __launch_bounds__(256) void wcolsum(const u16* __restrict__ ob,
                                               const float* __restrict__ w, int N,
                                               float* __restrict__ pp) {
    __shared__ float sh[4][256];
    const int lane = threadIdx.x & 63;
    const int wid = threadIdx.x >> 6;
    int wv = (blockIdx.x * blockDim.x + threadIdx.x) >> 6;
    int nw = (gridDim.x * blockDim.x) >> 6;
    float a0 = 0.f, a1 = 0.f, a2 = 0.f, a3 = 0.f;
    for (int n = wv; n < N; n += nw) {
        float wn = w[n];
        u16x4 hv = *reinterpret_cast<const u16x4*>(&ob[(size_t)n * 256 + lane * 4]);
        a0 = fmaf(wn, b2f((u16)hv[0]), a0);
        a1 = fmaf(wn, b2f((u16)hv[1]), a1);
        a2 = fmaf(wn, b2f((u16)hv[2]), a2);
        a3 = fmaf(wn, b2f((u16)hv[3]), a3);
    }
    sh[wid][lane * 4 + 0] = a0;
    sh[wid][lane * 4 + 1] = a1;
    sh[wid][lane * 4 + 2] = a2;
    sh[wid][lane * 4 + 3] = a3;
    __syncthreads();
    int t = threadIdx.x;
    float s = sh[0][t] + sh[1][t] + sh[2][t] + sh[3][t];
    atomicAdd(&pp[t], s);
}

__global__ void final_out(const float* __restrict__ pp, const float* __restrict__ W3,
                          const float* __restrict__ b3, int N, float* __restrict__ out) {
    __shared__ float acc[10];
    int t = threadIdx.x;  // 256
    if (t < 10) acc[t] = 0.f;
    __syncthreads();
    float pk = pp[t] / (float)N;
#pragma unroll
    for (int c = 0; c < 10; ++c) atomicAdd(&acc[c], pk * W3[t * 10 + c]);
    __syncthreads();
    if (t == 0) {
        float p[10];
        float mx = -INFINITY;
        for (int c = 0; c < 10; ++c) {
            p[c] = acc[c] + b3[c];
            mx = fmaxf(mx, p[c]);
        }
        float s = 0.f;
        for (int c = 0; c < 10; ++c) s += expf(p[c] - mx);
        float ls = logf(s);
        for (int c = 0; c < 10; ++c) out[c] = p[c] - mx - ls;
    }
}

extern "C" void kernel_launch(void* const* d_in, const int* in_sizes, int n_in,
                              void* d_out, int out_size, void* d_ws, size_t ws_size,
                              hipStream_t stream) {
    const float* x   = (const float*)d_in[0];
    const int*   ei  = (const int*)d_in[1];
    const float* W1  = (const float*)d_in[2];
    const float* as1 = (const float*)d_in[3];
    const float* ad1 = (const float*)d_in[4];
    const float* b1  = (const float*)d_in[5];
    const float* W2  = (const float*)d_in[6];
    const float* as2 = (const float*)d_in[7];
    const float* ad2 = (const float*)d_in[8];
    const float* b2  = (const float*)d_in[9];
    const float* W3  = (const float*)d_in[10];
    const float* as3 = (const float*)d_in[11];
    const float* ad3 = (const float*)d_in[12];
    const float* b3  = (const float*)d_in[13];
    float* out = (float*)d_out;

    const int N = in_sizes[0] / 128;   // 50000
    const int E = in_sizes[1] / 2;     // 800000
    const int Etot = E + N;
    const int NB = (N + 127) >> 7;     // 128-dst buckets (391)
    const int* srcI = ei;
    const int* dstI = ei + E;

    char* base = (char*)d_ws;
    size_t off = 0;
    auto alloc = [&](size_t bytes) {
        void* p = base + off;
        off = (off + bytes + 255) & ~(size_t)255;
        return p;
    };
    u16* x_bf  = (u16*)alloc((size_t)N * 128 * 2);
    u16* h_bf  = (u16*)alloc((size_t)N * 256 * 2);
    unsigned* h8 = (unsigned*)alloc((size_t)N * 256);
    u16* oa_bf = (u16*)alloc((size_t)N * 256 * 2);
    u16* ob_bf = (u16*)alloc((size_t)N * 256 * 2);
    u16* w1t   = (u16*)alloc(256 * 128 * 2);
    u16* w2t   = (u16*)alloc(256 * 256 * 2);
    float* pq   = (float*)alloc((size_t)N * 8 * 4);   // [n][4] float2
    float* al_d = (float*)alloc((size_t)N * 4 * 4);
    float* pq3  = (float*)alloc((size_t)N * 2 * 4);   // [n] float2
    // contiguous zero region: bcnt | wq | pp
    int* bcnt   = (int*)alloc(512 * 4);
    float* wq   = (float*)alloc((size_t)N * 4);
    float* pp   = (float*)alloc(256 * 4);
    int* rp     = (int*)alloc((size_t)(N + 1) * 4);
    int* bbase  = (int*)alloc(512 * 4);
    int* bcursor = (int*)alloc(512 * 4);
    unsigned* binned = (unsigned*)alloc((size_t)Etot * 4);
    u16* srcp   = (u16*)alloc((size_t)Etot * 2);

    // ---- prep: cast x, transpose weights, zero scratch (one dispatch) ----
    const int n4 = N * 128 / 4;
    const int B0 = (n4 + 255) / 256;
    const int B1 = B0 + (128 * 256 + 255) / 256;
    const int B2 = B1 + (256 * 256 + 255) / 256;
    int span = (int)(((char*)(pp + 256) - (char*)bcnt) / 4);
    const int B3 = B2 + (span + 255) / 256;
    prep<<<B3, 256, 0, stream>>>(x, x_bf, n4, W1, w1t, W2, w2t,
                                 bcnt, span, B0, B1, B2);

    // ---- bucketed CSR build ----
    bucket_hist<<<(Etot + 2047) / 2048, 256, 0, stream>>>(dstI, E, Etot, bcnt, NB);
    bucket_scan<<<1, 512, 0, stream>>>(bcnt, NB, Etot, bbase, bcursor, rp, N);
    bin_scatter<<<(Etot + 256 * EPB - 1) / (256 * EPB), 256, 0, stream>>>(
        srcI, dstI, E, Etot, bcursor, binned, NB);
    bucket_csr<<<NB, 256, 0, stream>>>(binned, bbase, N, rp, srcp);

    const int FUSED_BLOCKS = (N + 3) / 4;
    const int ALC_BLOCKS = (N / 2 + 3) / 4;   // 2 nodes per wave, 4 waves/block
    const int GX = (N + 127) / 128;

    // ---- layer 1: x_bf[N,128] -> oa_bf[N,256], ELU ----
    {
        dim3 g(GX, 2);
        gemm_mfma<<<g, 256, 0, stream>>>(x_bf, w1t, h_bf, N, 128, 256);
        compute_al_cast<<<ALC_BLOCKS, 256, 0, stream>>>(h_bf, as1, ad1, N,
                                                        pq, al_d, h8);
        gat_fused_h4<true><<<FUSED_BLOCKS, 256, 0, stream>>>(
            h8, pq, al_d, b1, rp, srcp, N, oa_bf);
    }
    // ---- layer 2: oa_bf -> ob_bf, ELU ----
    {
        dim3 g(GX, 2);
        gemm_mfma<<<g, 256, 0, stream>>>(oa_bf, w2t, h_bf, N, 256, 256);
        compute_al_cast<<<ALC_BLOCKS, 256, 0, stream>>>(h_bf, as2, ad2, N,
                                                        pq, al_d, h8);
        gat_fused_h4<true><<<FUSED_BLOCKS, 256, 0, stream>>>(
            h8, pq, al_d, b2, rp, srcp, N, ob_bf);
    }
    // ---- layer 3 (linear-collapsed): pooled = (1/N * sum_s w_s ob_s) @ W3 + b3
    {
        compute_al3<<<(N + 3) / 4, 256, 0, stream>>>(ob_bf, W3, as3, ad3, N, pq3, al_d);
        l3_edge<<<(N + 3) / 4, 256, 0, stream>>>(pq3, al_d, rp, srcp, N, wq);
        wcolsum<<<1024, 256, 0, stream>>>(ob_bf, wq, N, pp);
        final_out<<<1, 256, 0, stream>>>(pp, W3, b3, N, out);
    }
}

// Round 12
// 320.416 us; speedup vs baseline: 1.4111x; 1.0350x over previous
//
#include <hip/hip_runtime.h>
#include <math.h>

#define NEG_SLOPE 0.2f

typedef __attribute__((ext_vector_type(8))) short bf16x8;
typedef __attribute__((ext_vector_type(4))) float f32x4;
typedef __attribute__((ext_vector_type(2))) float f32x2;
typedef unsigned short u16;
typedef __attribute__((ext_vector_type(4))) unsigned short u16x4;
typedef __attribute__((ext_vector_type(8))) unsigned short u16x8;

__device__ __forceinline__ float b2f(u16 u) {
    return __uint_as_float(((unsigned)u) << 16);
}
__device__ __forceinline__ u16 f2b(float f) {
    unsigned u = __float_as_uint(f);
    unsigned r = (u + 0x7fffu + ((u >> 16) & 1u)) >> 16;
    return (u16)r;
}

// ---------------- fused prep: cast x, transpose W1/W2, zero scratch --------
__global__ void prep(const float* __restrict__ x, u16* __restrict__ x_bf, int n4,
                     const float* __restrict__ W1, u16* __restrict__ w1t,
                     const float* __restrict__ W2, u16* __restrict__ w2t,
                     int* __restrict__ zero_base, int nzero,
                     int B0, int B1, int B2) {
    int blk = blockIdx.x;
    if (blk < B0) {
        int i = blk * 256 + threadIdx.x;
        if (i < n4) {
            float4 v = *reinterpret_cast<const float4*>(&x[i * 4]);
            u16x4 o;
            o[0] = f2b(v.x); o[1] = f2b(v.y); o[2] = f2b(v.z); o[3] = f2b(v.w);
            *reinterpret_cast<u16x4*>(&x_bf[i * 4]) = o;
        }
    } else if (blk < B1) {
        int i = (blk - B0) * 256 + threadIdx.x;  // [M][K], K=128, M=256
        if (i < 128 * 256) {
            int m = i >> 7, k = i & 127;
            w1t[i] = f2b(W1[(size_t)k * 256 + m]);
        }
    } else if (blk < B2) {
        int i = (blk - B1) * 256 + threadIdx.x;  // K=256, M=256
        if (i < 256 * 256) {
            int m = i >> 8, k = i & 255;
            w2t[i] = f2b(W2[(size_t)k * 256 + m]);
        }
    } else {
        int i = (blk - B2) * 256 + threadIdx.x;
        if (i < nzero) zero_base[i] = 0;
    }
}

// ---- MFMA GEMM (M=256) with fused epilogue: fp8 h, pq=(e^al_s,e^.2al_s), al_d
// Each wave owns 64 rows x 64 cols = one head's full channel range.
__global__ __launch_bounds__(256) void gemm_mfma_fused(
        const u16* __restrict__ A, const u16* __restrict__ Bt,
        int N, int K,
        const float* __restrict__ a_s, const float* __restrict__ a_d,
        unsigned char* __restrict__ h8b, float* __restrict__ pq,
        float* __restrict__ al_d) {
    __shared__ u16 As[128 * 64];
    __shared__ u16 Bs[128 * 64];
    const int tid = threadIdx.x;
    const int lane = tid & 63;
    const int wid = tid >> 6;
    const int wr = wid >> 1, wc = wid & 1;
    const int row0 = blockIdx.x * 128;
    const int col0 = blockIdx.y * 128;
    f32x4 acc[4][4] = {};
    for (int k0 = 0; k0 < K; k0 += 64) {
        if (k0) __syncthreads();
#pragma unroll
        for (int i = 0; i < 4; ++i) {
            int chunk = i * 256 + tid;
            int row = chunk >> 3;
            int slot = chunk & 7;
            int grow = row0 + row; if (grow >= N) grow = N - 1;
            bf16x8 v = *reinterpret_cast<const bf16x8*>(&A[(size_t)grow * K + k0 + slot * 8]);
            int swz = (chunk & ~7) | (slot ^ (row & 7));
            *reinterpret_cast<bf16x8*>(&As[swz * 8]) = v;
        }
#pragma unroll
        for (int i = 0; i < 4; ++i) {
            int chunk = i * 256 + tid;
            int row = chunk >> 3;
            int slot = chunk & 7;
            int gcol = col0 + row;
            bf16x8 v = *reinterpret_cast<const bf16x8*>(&Bt[(size_t)gcol * K + k0 + slot * 8]);
            int swz = (chunk & ~7) | (slot ^ (row & 7));
            *reinterpret_cast<bf16x8*>(&Bs[swz * 8]) = v;
        }
        __syncthreads();
#pragma unroll
        for (int kk = 0; kk < 2; ++kk) {
            bf16x8 ax[4], bx[4];
#pragma unroll
            for (int m = 0; m < 4; ++m) {
                int row = wr * 64 + m * 16 + (lane & 15);
                int slot = kk * 4 + (lane >> 4);
                ax[m] = *reinterpret_cast<const bf16x8*>(&As[(row * 8 + (slot ^ (row & 7))) * 8]);
            }
#pragma unroll
            for (int n = 0; n < 4; ++n) {
                int row = wc * 64 + n * 16 + (lane & 15);
                int slot = kk * 4 + (lane >> 4);
                bx[n] = *reinterpret_cast<const bf16x8*>(&Bs[(row * 8 + (slot ^ (row & 7))) * 8]);
            }
#pragma unroll
            for (int m = 0; m < 4; ++m)
#pragma unroll
                for (int n = 0; n < 4; ++n)
                    acc[m][n] = __builtin_amdgcn_mfma_f32_16x16x32_bf16(
                        ax[m], bx[n], acc[m][n], 0, 0, 0);
        }
    }
    // ---- fused epilogue ----
    const int head = blockIdx.y * 2 + wc;        // wave's head
    float asf[4], adf[4];
#pragma unroll
    for (int n = 0; n < 4; ++n) {
        asf[n] = a_s[head * 64 + n * 16 + (lane & 15)];
        adf[n] = a_d[head * 64 + n * 16 + (lane & 15)];
    }
    const int crow = row0 + wr * 64;
#pragma unroll
    for (int m = 0; m < 4; ++m) {
#pragma unroll
        for (int r = 0; r < 4; ++r) {
            float ss = 0.f, sd = 0.f;
#pragma unroll
            for (int n = 0; n < 4; ++n) {
                float v = acc[m][n][r];
                ss = fmaf(v, asf[n], ss);
                sd = fmaf(v, adf[n], sd);
            }
#pragma unroll
            for (int msk = 1; msk < 16; msk <<= 1) {
                ss += __shfl_xor(ss, msk, 64);
                sd += __shfl_xor(sd, msk, 64);
            }
            int rg = crow + m * 16 + (lane >> 4) * 4 + r;
            if (rg < N) {
                if ((lane & 15) == 0) {
                    f32x2 pv; pv.x = __expf(ss); pv.y = __expf(NEG_SLOPE * ss);
                    *reinterpret_cast<f32x2*>(&pq[(size_t)rg * 8 + head * 2]) = pv;
                    al_d[rg * 4 + head] = sd;
                }
#pragma unroll
                for (int n = 0; n < 4; ++n) {
                    int w8 = __builtin_amdgcn_cvt_pk_fp8_f32(acc[m][n][r], acc[m][n][r], 0, false);
                    h8b[(size_t)rg * 256 + head * 64 + n * 16 + (lane & 15)] =
                        (unsigned char)(w8 & 0xFF);
                }
            }
        }
    }
}

// ================= bucketed CSR build (128-dst buckets) =====================
__global__ __launch_bounds__(256) void bucket_hist(
        const int* __restrict__ dstI, int E, int Etot,
        int* __restrict__ bcnt, int NB) {
    __shared__ int h[512];
    int t = threadIdx.x;
    for (int j = t; j < NB; j += 256) h[j] = 0;
    __syncthreads();
    int base = blockIdx.x * 2048;
#pragma unroll
    for (int j = 0; j < 8; ++j) {
        int e = base + j * 256 + t;
        if (e < Etot) {
            int d = (e < E) ? dstI[e] : (e - E);
            atomicAdd(&h[d >> 7], 1);
        }
    }
    __syncthreads();
    for (int j = t; j < NB; j += 256)
        if (h[j]) atomicAdd(&bcnt[j], h[j]);
}

__global__ __launch_bounds__(512) void bucket_scan(
        const int* __restrict__ bcnt, int NB, int Etot,
        int* __restrict__ bbase, int* __restrict__ bcursor,
        int* __restrict__ rp, int N) {
    __shared__ int a[512], b[512];
    int t = threadIdx.x;
    a[t] = (t < NB) ? bcnt[t] : 0;
    __syncthreads();
    int* s = a; int* d = b;
    for (int ofs = 1; ofs < 512; ofs <<= 1) {
        d[t] = (t >= ofs) ? s[t] + s[t - ofs] : s[t];
        __syncthreads();
        int* tmp = s; s = d; d = tmp;
    }
    int excl = (t == 0) ? 0 : s[t - 1];
    if (t < NB) { bbase[t] = excl; bcursor[t] = excl; }
    if (t == NB) bbase[NB] = Etot;
    if (t == 0) rp[N] = Etot;
}

#define EPB 16
__global__ __launch_bounds__(256) void bin_scatter(
        const int* __restrict__ srcI, const int* __restrict__ dstI,
        int E, int Etot, int* __restrict__ bcursor,
        unsigned* __restrict__ binned, int NB) {
    __shared__ int cnt[512];
    int t = threadIdx.x;
    for (int j = t; j < NB; j += 256) cnt[j] = 0;
    __syncthreads();
    int base_e = blockIdx.x * (256 * EPB) + t;
    unsigned rec[EPB];
    int bkt[EPB];
#pragma unroll
    for (int j = 0; j < EPB; ++j) {
        int e = base_e + j * 256;
        bkt[j] = -1;
        if (e < Etot) {
            int s = (e < E) ? srcI[e] : (e - E);
            int d = (e < E) ? dstI[e] : (e - E);
            bkt[j] = d >> 7;
            rec[j] = ((unsigned)(d & 127) << 16) | (unsigned)s;
            atomicAdd(&cnt[bkt[j]], 1);
        }
    }
    __syncthreads();
    for (int j = t; j < NB; j += 256) {
        int c = cnt[j];
        cnt[j] = c ? atomicAdd(&bcursor[j], c) : 0;
    }
    __syncthreads();
#pragma unroll
    for (int j = 0; j < EPB; ++j)
        if (bkt[j] >= 0) {
            int pos = atomicAdd(&cnt[bkt[j]], 1);
            binned[pos] = rec[j];
        }
}

__global__ __launch_bounds__(256) void bucket_csr(
        const unsigned* __restrict__ binned, const int* __restrict__ bbase,
        int N, int* __restrict__ rp, u16* __restrict__ srcp) {
    int b = blockIdx.x;
    int start = bbase[b];
    int cnt = bbase[b + 1] - start;
    __shared__ int dcnt[128];
    __shared__ int dofs[128];
    __shared__ int wtot;
    int t = threadIdx.x;
    if (t < 128) dcnt[t] = 0;
    __syncthreads();
    for (int i = t; i < cnt; i += 256)
        atomicAdd(&dcnt[binned[start + i] >> 16], 1);
    __syncthreads();
    int v = 0, x = 0;
    if (t < 128) {
        v = dcnt[t];
        x = v;
#pragma unroll
        for (int ofs = 1; ofs < 64; ofs <<= 1) {
            int u = __shfl_up(x, ofs, 64);
            if ((t & 63) >= ofs) x += u;
        }
    }
    if (t == 63) wtot = x;
    __syncthreads();
    if (t >= 64 && t < 128) x += wtot;
    if (t < 128) {
        int abs0 = start + (x - v);
        int d = b * 128 + t;
        if (d < N) rp[d] = abs0;
        dofs[t] = abs0;
    }
    __syncthreads();
    for (int i = t; i < cnt; i += 256) {
        unsigned rec = binned[start + i];
        int pos = atomicAdd(&dofs[rec >> 16], 1);
        srcp[pos] = (u16)(rec & 0xFFFFu);
    }
}

// ----- single-pass fused aggregate: half-wave per edge, fp8 gather ---------
template<bool ELU>
__global__ __launch_bounds__(256) void gat_fused_h4(
        const unsigned* __restrict__ h8, const float* __restrict__ pq,
        const float* __restrict__ al_d, const float* __restrict__ b,
        const int* __restrict__ rp, const u16* __restrict__ srcp,
        int N, u16* __restrict__ out) {
    const int lane = threadIdx.x & 63;
    const int hlf = lane >> 5;          // half owns alternating edges
    const int l = lane & 31;            // lane covers channels [8l, 8l+8)
    const int head = l >> 3;
    int w = (blockIdx.x * blockDim.x + threadIdx.x) >> 6;
    int nw = (gridDim.x * blockDim.x) >> 6;
    for (int d = w; d < N; d += nw) {
        int start = rp[d], end = rp[d + 1];
        float ald = al_d[d * 4 + head];
        float pb = __expf(ald);
        float qb = __expf(NEG_SLOPE * ald);
        float a0 = 0, a1 = 0, a2 = 0, a3 = 0, a4 = 0, a5 = 0, a6 = 0, a7 = 0, L = 0;

#define EDGE1(S) {                                                              \
        unsigned s_ = (S);                                                      \
        uint2 hv_ = *reinterpret_cast<const uint2*>(&h8[s_ * 64u + (unsigned)l * 2u]); \
        f32x2 pv_ = *reinterpret_cast<const f32x2*>(&pq[s_ * 8u + (unsigned)head * 2u]); \
        float t_ = pv_.x * pb;                                                  \
        float e_ = (t_ > 1.f) ? t_ : pv_.y * qb;                                \
        L += e_;                                                                \
        f32x2 p0_ = __builtin_amdgcn_cvt_pk_f32_fp8((int)hv_.x, false);         \
        f32x2 p1_ = __builtin_amdgcn_cvt_pk_f32_fp8((int)hv_.x, true);          \
        f32x2 p2_ = __builtin_amdgcn_cvt_pk_f32_fp8((int)hv_.y, false);         \
        f32x2 p3_ = __builtin_amdgcn_cvt_pk_f32_fp8((int)hv_.y, true);          \
        a0 = fmaf(e_, p0_.x, a0); a1 = fmaf(e_, p0_.y, a1);                     \
        a2 = fmaf(e_, p1_.x, a2); a3 = fmaf(e_, p1_.y, a3);                     \
        a4 = fmaf(e_, p2_.x, a4); a5 = fmaf(e_, p2_.y, a5);                     \
        a6 = fmaf(e_, p3_.x, a6); a7 = fmaf(e_, p3_.y, a7); }

        int i = start;
        int pre = (4 - (i & 3)) & 3;
        if (pre > end - i) pre = end - i;
        for (int k = hlf; k < pre; k += 2) EDGE1(srcp[i + k]);
        i += pre;
        int nb = (end - i) & ~7;
        int stop = i + nb;
        for (int j = i + hlf * 4; j < stop; j += 8) {
            u16x4 sv = *reinterpret_cast<const u16x4*>(&srcp[j]);
            unsigned s4[4] = {sv[0], sv[1], sv[2], sv[3]};
            uint2 hv[4]; f32x2 pv[4];
#pragma unroll
            for (int q = 0; q < 4; ++q) {
                hv[q] = *reinterpret_cast<const uint2*>(&h8[s4[q] * 64u + (unsigned)l * 2u]);
                pv[q] = *reinterpret_cast<const f32x2*>(&pq[s4[q] * 8u + (unsigned)head * 2u]);
            }
#pragma unroll
            for (int q = 0; q < 4; ++q) {
                float t = pv[q].x * pb;
                float e = (t > 1.f) ? t : pv[q].y * qb;
                L += e;
                f32x2 p0 = __builtin_amdgcn_cvt_pk_f32_fp8((int)hv[q].x, false);
                f32x2 p1 = __builtin_amdgcn_cvt_pk_f32_fp8((int)hv[q].x, true);
                f32x2 p2 = __builtin_amdgcn_cvt_pk_f32_fp8((int)hv[q].y, false);
                f32x2 p3 = __builtin_amdgcn_cvt_pk_f32_fp8((int)hv[q].y, true);
                a0 = fmaf(e, p0.x, a0); a1 = fmaf(e, p0.y, a1);
                a2 = fmaf(e, p1.x, a2); a3 = fmaf(e, p1.y, a3);
                a4 = fmaf(e, p2.x, a4); a5 = fmaf(e, p2.y, a5);
                a6 = fmaf(e, p3.x, a6); a7 = fmaf(e, p3.y, a7);
            }
        }
        for (int k = stop + hlf; k < end; k += 2) EDGE1(srcp[k]);
#undef EDGE1

        // combine halves
        a0 += __shfl_xor(a0, 32, 64); a1 += __shfl_xor(a1, 32, 64);
        a2 += __shfl_xor(a2, 32, 64); a3 += __shfl_xor(a3, 32, 64);
        a4 += __shfl_xor(a4, 32, 64); a5 += __shfl_xor(a5, 32, 64);
        a6 += __shfl_xor(a6, 32, 64); a7 += __shfl_xor(a7, 32, 64);
        L += __shfl_xor(L, 32, 64);
        float inv = 1.f / (L + 1e-16f);
        if (hlf == 0) {
            float4 b0 = *reinterpret_cast<const float4*>(&b[l * 8]);
            float4 b1 = *reinterpret_cast<const float4*>(&b[l * 8 + 4]);
            float o0 = fmaf(a0, inv, b0.x), o1 = fmaf(a1, inv, b0.y);
            float o2 = fmaf(a2, inv, b0.z), o3 = fmaf(a3, inv, b0.w);
            float o4 = fmaf(a4, inv, b1.x), o5 = fmaf(a5, inv, b1.y);
            float o6 = fmaf(a6, inv, b1.z), o7 = fmaf(a7, inv, b1.w);
            if (ELU) {
                o0 = (o0 > 0.f) ? o0 : expm1f(o0);
                o1 = (o1 > 0.f) ? o1 : expm1f(o1);
                o2 = (o2 > 0.f) ? o2 : expm1f(o2);
                o3 = (o3 > 0.f) ? o3 : expm1f(o3);
                o4 = (o4 > 0.f) ? o4 : expm1f(o4);
                o5 = (o5 > 0.f) ? o5 : expm1f(o5);
                o6 = (o6 > 0.f) ? o6 : expm1f(o6);
                o7 = (o7 > 0.f) ? o7 : expm1f(o7);
            }
            u16x8 ov;
            ov[0] = f2b(o0); ov[1] = f2b(o1); ov[2] = f2b(o2); ov[3] = f2b(o3);
            ov[4] = f2b(o4); ov[5] = f2b(o5); ov[6] = f2b(o6); ov[7] = f2b(o7);
            *reinterpret_cast<u16x8*>(&out[(size_t)d * 256 + l * 8]) = ov;
        }
    }
}

// ================= layer-3 linear-collapse path =============================
__global__ __launch_bounds__(256) void compute_al3(
        const u16* __restrict__ ob, const float* __restrict__ W3,
        const float* __restrict__ as3, const float* __restrict__ ad3, int N,
        float* __restrict__ pq3, float* __restrict__ al_d) {
    __shared__ float was[256], wad[256];
    {
        int t = threadIdx.x;
        float ss = 0.f, sd = 0.f;
#pragma unroll
        for (int c = 0; c < 10; ++c) {
            float w = W3[t * 10 + c];
            ss = fmaf(w, as3[c], ss);
            sd = fmaf(w, ad3[c], sd);
        }
        was[t] = ss; wad[t] = sd;
    }
    __syncthreads();
    const int lane = threadIdx.x & 63;
    int n = (blockIdx.x * blockDim.x + threadIdx.x) >> 6;
    if (n >= N) return;
    u16x4 hv = *reinterpret_cast<const u16x4*>(&ob[(size_t)n * 256 + lane * 4]);
    float4 ws = *reinterpret_cast<const float4*>(&was[lane * 4]);
    float4 wd = *reinterpret_cast<const float4*>(&wad[lane * 4]);
    float f0 = b2f((u16)hv[0]), f1 = b2f((u16)hv[1]);
    float f2 = b2f((u16)hv[2]), f3 = b2f((u16)hv[3]);
    float ss = f0 * ws.x + f1 * ws.y + f2 * ws.z + f3 * ws.w;
    float sd = f0 * wd.x + f1 * wd.y + f2 * wd.z + f3 * wd.w;
#pragma unroll
    for (int m = 1; m < 64; m <<= 1) {
        ss += __shfl_xor(ss, m, 64);
        sd += __shfl_xor(sd, m, 64);
    }
    if (lane == 0) {
        f32x2 pv; pv.x = __expf(ss); pv.y = __expf(NEG_SLOPE * ss);
        *reinterpret_cast<f32x2*>(&pq3[(size_t)n * 2]) = pv;
        al_d[n] = sd;
    }
}

__global__ __launch_bounds__(256) void l3_edge(
        const float* __restrict__ pq3, const float* __restrict__ al_d,
        const int* __restrict__ rp, const u16* __restrict__ srcp,
        int N, float* __restrict__ wq) {
    const int lane = threadIdx.x & 63;
    int w = (blockIdx.x * blockDim.x + threadIdx.x) >> 6;
    int nw = (gridDim.x * blockDim.x) >> 6;
    for (int d = w; d < N; d += nw) {
        int start = rp[d], end = rp[d + 1];
        float ald = al_d[d];
        float pb = __expf(ald);
        float qb = __expf(NEG_SLOPE * ald);
        float L = 0.f;
        for (int i = start + lane; i < end; i += 64) {
            f32x2 pqv = *reinterpret_cast<const f32x2*>(&pq3[(unsigned)srcp[i] * 2u]);
            float t = pqv.x * pb;
            L += (t > 1.f) ? t : pqv.y * qb;
        }
#pragma unroll
        for (int m = 1; m < 64; m <<= 1) L += __shfl_xor(L, m, 64);
        float inv = 1.f / (L + 1e-16f);
        for (int i = start + lane; i < end; i += 64) {
            unsigned s = srcp[i];
            f32x2 pqv = *reinterpret_cast<const f32x2*>(&pq3[s * 2u]);
            float t = pqv.x * pb;
            float e = (t > 1.f) ? t : pqv.y * qb;
            atomicAdd(&wq[s], e * inv);
        }
    }
}

__global__ __launch_bounds__(256) void wcolsum(const u16* __restrict__ ob,
                                               const float* __restrict__ w, int N,
                                               float* __restrict__ pp) {
    __shared__ float sh[4][256];
    const int lane = threadIdx.x & 63;
    const int wid = threadIdx.x >> 6;
    int wv = (blockIdx.x * blockDim.x + threadIdx.x) >> 6;
    int nw = (gridDim.x * blockDim.x) >> 6;
    float a0 = 0.f, a1 = 0.f, a2 = 0.f, a3 = 0.f;
    for (int n = wv; n < N; n += nw) {
        float wn = w[n];
        u16x4 hv = *reinterpret_cast<const u16x4*>(&ob[(size_t)n * 256 + lane * 4]);
        a0 = fmaf(wn, b2f((u16)hv[0]), a0);
        a1 = fmaf(wn, b2f((u16)hv[1]), a1);
        a2 = fmaf(wn, b2f((u16)hv[2]), a2);
        a3 = fmaf(wn, b2f((u16)hv[3]), a3);
    }
    sh[wid][lane * 4 + 0] = a0;
    sh[wid][lane * 4 + 1] = a1;
    sh[wid][lane * 4 + 2] = a2;
    sh[wid][lane * 4 + 3] = a3;
    __syncthreads();
    int t = threadIdx.x;
    float s = sh[0][t] + sh[1][t] + sh[2][t] + sh[3][t];
    atomicAdd(&pp[t], s);
}

__global__ void final_out(const float* __restrict__ pp, const float* __restrict__ W3,
                          const float* __restrict__ b3, int N, float* __restrict__ out) {
    __shared__ float acc[10];
    int t = threadIdx.x;  // 256
    if (t < 10) acc[t] = 0.f;
    __syncthreads();
    float pk = pp[t] / (float)N;
#pragma unroll
    for (int c = 0; c < 10; ++c) atomicAdd(&acc[c], pk * W3[t * 10 + c]);
    __syncthreads();
    if (t == 0) {
        float p[10];
        float mx = -INFINITY;
        for (int c = 0; c < 10; ++c) {
            p[c] = acc[c] + b3[c];
            mx = fmaxf(mx, p[c]);
        }
        float s = 0.f;
        for (int c = 0; c < 10; ++c) s += expf(p[c] - mx);
        float ls = logf(s);
        for (int c = 0; c < 10; ++c) out[c] = p[c] - mx - ls;
    }
}

extern "C" void kernel_launch(void* const* d_in, const int* in_sizes, int n_in,
                              void* d_out, int out_size, void* d_ws, size_t ws_size,
                              hipStream_t stream) {
    const float* x   = (const float*)d_in[0];
    const int*   ei  = (const int*)d_in[1];
    const float* W1  = (const float*)d_in[2];
    const float* as1 = (const float*)d_in[3];
    const float* ad1 = (const float*)d_in[4];
    const float* b1  = (const float*)d_in[5];
    const float* W2  = (const float*)d_in[6];
    const float* as2 = (const float*)d_in[7];
    const float* ad2 = (const float*)d_in[8];
    const float* b2  = (const float*)d_in[9];
    const float* W3  = (const float*)d_in[10];
    const float* as3 = (const float*)d_in[11];
    const float* ad3 = (const float*)d_in[12];
    const float* b3  = (const float*)d_in[13];
    float* out = (float*)d_out;

    const int N = in_sizes[0] / 128;   // 50000
    const int E = in_sizes[1] / 2;     // 800000
    const int Etot = E + N;
    const int NB = (N + 127) >> 7;     // 128-dst buckets
    const int* srcI = ei;
    const int* dstI = ei + E;

    char* base = (char*)d_ws;
    size_t off = 0;
    auto alloc = [&](size_t bytes) {
        void* p = base + off;
        off = (off + bytes + 255) & ~(size_t)255;
        return p;
    };
    u16* x_bf  = (u16*)alloc((size_t)N * 128 * 2);
    unsigned* h8 = (unsigned*)alloc((size_t)N * 256);
    u16* oa_bf = (u16*)alloc((size_t)N * 256 * 2);
    u16* ob_bf = (u16*)alloc((size_t)N * 256 * 2);
    u16* w1t   = (u16*)alloc(256 * 128 * 2);
    u16* w2t   = (u16*)alloc(256 * 256 * 2);
    float* pq   = (float*)alloc((size_t)N * 8 * 4);   // [n][4] float2
    float* al_d = (float*)alloc((size_t)N * 4 * 4);
    float* pq3  = (float*)alloc((size_t)N * 2 * 4);   // [n] float2
    // contiguous zero region: bcnt | wq | pp
    int* bcnt   = (int*)alloc(512 * 4);
    float* wq   = (float*)alloc((size_t)N * 4);
    float* pp   = (float*)alloc(256 * 4);
    int* rp     = (int*)alloc((size_t)(N + 1) * 4);
    int* bbase  = (int*)alloc(512 * 4);
    int* bcursor = (int*)alloc(512 * 4);
    unsigned* binned = (unsigned*)alloc((size_t)Etot * 4);
    u16* srcp   = (u16*)alloc((size_t)Etot * 2);

    // ---- prep: cast x, transpose weights, zero scratch (one dispatch) ----
    const int n4 = N * 128 / 4;
    const int B0 = (n4 + 255) / 256;
    const int B1 = B0 + (128 * 256 + 255) / 256;
    const int B2 = B1 + (256 * 256 + 255) / 256;
    int span = (int)(((char*)(pp + 256) - (char*)bcnt) / 4);
    const int B3 = B2 + (span + 255) / 256;
    prep<<<B3, 256, 0, stream>>>(x, x_bf, n4, W1, w1t, W2, w2t,
                                 bcnt, span, B0, B1, B2);

    // ---- bucketed CSR build ----
    bucket_hist<<<(Etot + 2047) / 2048, 256, 0, stream>>>(dstI, E, Etot, bcnt, NB);
    bucket_scan<<<1, 512, 0, stream>>>(bcnt, NB, Etot, bbase, bcursor, rp, N);
    bin_scatter<<<(Etot + 256 * EPB - 1) / (256 * EPB), 256, 0, stream>>>(
        srcI, dstI, E, Etot, bcursor, binned, NB);
    bucket_csr<<<NB, 256, 0, stream>>>(binned, bbase, N, rp, srcp);

    const int FUSED_BLOCKS = (N + 3) / 4;
    const int GX = (N + 127) / 128;

    // ---- layer 1: x_bf[N,128] -> oa_bf[N,256], ELU ----
    {
        dim3 g(GX, 2);
        gemm_mfma_fused<<<g, 256, 0, stream>>>(x_bf, w1t, N, 128, as1, ad1,
                                               (unsigned char*)h8, pq, al_d);
        gat_fused_h4<true><<<FUSED_BLOCKS, 256, 0, stream>>>(
            h8, pq, al_d, b1, rp, srcp, N, oa_bf);
    }
    // ---- layer 2: oa_bf -> ob_bf, ELU ----
    {
        dim3 g(GX, 2);
        gemm_mfma_fused<<<g, 256, 0, stream>>>(oa_bf, w2t, N, 256, as2, ad2,
                                               (unsigned char*)h8, pq, al_d);
        gat_fused_h4<true><<<FUSED_BLOCKS, 256, 0, stream>>>(
            h8, pq, al_d, b2, rp, srcp, N, ob_bf);
    }
    // ---- layer 3 (linear-collapsed): pooled = (1/N * sum_s w_s ob_s) @ W3 + b3
    {
        compute_al3<<<(N + 3) / 4, 256, 0, stream>>>(ob_bf, W3, as3, ad3, N, pq3, al_d);
        l3_edge<<<(N + 3) / 4, 256, 0, stream>>>(pq3, al_d, rp, srcp, N, wq);
        wcolsum<<<1024, 256, 0, stream>>>(ob_bf, wq, N, pp);
        final_out<<<1, 256, 0, stream>>>(pp, W3, b3, N, out);
    }
}

// Round 14
// 320.203 us; speedup vs baseline: 1.4120x; 1.0007x over previous
//
#include <hip/hip_runtime.h>
#include <math.h>

#define NEG_SLOPE 0.2f

typedef __attribute__((ext_vector_type(8))) short bf16x8;
typedef __attribute__((ext_vector_type(4))) float f32x4;
typedef __attribute__((ext_vector_type(2))) float f32x2;
typedef unsigned short u16;
typedef __attribute__((ext_vector_type(4))) unsigned short u16x4;
typedef __attribute__((ext_vector_type(8))) unsigned short u16x8;

__device__ __forceinline__ float b2f(u16 u) {
    return __uint_as_float(((unsigned)u) << 16);
}
__device__ __forceinline__ u16 f2b(float f) {
    unsigned u = __float_as_uint(f);
    unsigned r = (u + 0x7fffu + ((u >> 16) & 1u)) >> 16;
    return (u16)r;
}

// ---------------- fused prep: cast x, transpose W1/W2, zero scratch --------
__global__ void prep(const float* __restrict__ x, u16* __restrict__ x_bf, int n4,
                     const float* __restrict__ W1, u16* __restrict__ w1t,
                     const float* __restrict__ W2, u16* __restrict__ w2t,
                     int* __restrict__ zero_base, int nzero,
                     int B0, int B1, int B2) {
    int blk = blockIdx.x;
    if (blk < B0) {
        int i = blk * 256 + threadIdx.x;
        if (i < n4) {
            float4 v = *reinterpret_cast<const float4*>(&x[i * 4]);
            u16x4 o;
            o[0] = f2b(v.x); o[1] = f2b(v.y); o[2] = f2b(v.z); o[3] = f2b(v.w);
            *reinterpret_cast<u16x4*>(&x_bf[i * 4]) = o;
        }
    } else if (blk < B1) {
        int i = (blk - B0) * 256 + threadIdx.x;  // [M][K], K=128, M=256
        if (i < 128 * 256) {
            int m = i >> 7, k = i & 127;
            w1t[i] = f2b(W1[(size_t)k * 256 + m]);
        }
    } else if (blk < B2) {
        int i = (blk - B1) * 256 + threadIdx.x;  // K=256, M=256
        if (i < 256 * 256) {
            int m = i >> 8, k = i & 255;
            w2t[i] = f2b(W2[(size_t)k * 256 + m]);
        }
    } else {
        int i = (blk - B2) * 256 + threadIdx.x;
        if (i < nzero) zero_base[i] = 0;
    }
}

// ---- MFMA GEMM (M=256) with fused epilogue: fp8 h, pq=(e^al_s,e^.2al_s), al_d
// Each wave owns 64 rows x 64 cols = one head's full channel range.
__global__ __launch_bounds__(256) void gemm_mfma_fused(
        const u16* __restrict__ A, const u16* __restrict__ Bt,
        int N, int K,
        const float* __restrict__ a_s, const float* __restrict__ a_d,
        unsigned char* __restrict__ h8b, float* __restrict__ pq,
        float* __restrict__ al_d) {
    __shared__ u16 As[128 * 64];
    __shared__ u16 Bs[128 * 64];
    const int tid = threadIdx.x;
    const int lane = tid & 63;
    const int wid = tid >> 6;
    const int wr = wid >> 1, wc = wid & 1;
    const int row0 = blockIdx.x * 128;
    const int col0 = blockIdx.y * 128;
    f32x4 acc[4][4] = {};
    for (int k0 = 0; k0 < K; k0 += 64) {
        if (k0) __syncthreads();
#pragma unroll
        for (int i = 0; i < 4; ++i) {
            int chunk = i * 256 + tid;
            int row = chunk >> 3;
            int slot = chunk & 7;
            int grow = row0 + row; if (grow >= N) grow = N - 1;
            bf16x8 v = *reinterpret_cast<const bf16x8*>(&A[(size_t)grow * K + k0 + slot * 8]);
            int swz = (chunk & ~7) | (slot ^ (row & 7));
            *reinterpret_cast<bf16x8*>(&As[swz * 8]) = v;
        }
#pragma unroll
        for (int i = 0; i < 4; ++i) {
            int chunk = i * 256 + tid;
            int row = chunk >> 3;
            int slot = chunk & 7;
            int gcol = col0 + row;
            bf16x8 v = *reinterpret_cast<const bf16x8*>(&Bt[(size_t)gcol * K + k0 + slot * 8]);
            int swz = (chunk & ~7) | (slot ^ (row & 7));
            *reinterpret_cast<bf16x8*>(&Bs[swz * 8]) = v;
        }
        __syncthreads();
#pragma unroll
        for (int kk = 0; kk < 2; ++kk) {
            bf16x8 ax[4], bx[4];
#pragma unroll
            for (int m = 0; m < 4; ++m) {
                int row = wr * 64 + m * 16 + (lane & 15);
                int slot = kk * 4 + (lane >> 4);
                ax[m] = *reinterpret_cast<const bf16x8*>(&As[(row * 8 + (slot ^ (row & 7))) * 8]);
            }
#pragma unroll
            for (int n = 0; n < 4; ++n) {
                int row = wc * 64 + n * 16 + (lane & 15);
                int slot = kk * 4 + (lane >> 4);
                bx[n] = *reinterpret_cast<const bf16x8*>(&Bs[(row * 8 + (slot ^ (row & 7))) * 8]);
            }
#pragma unroll
            for (int m = 0; m < 4; ++m)
#pragma unroll
                for (int n = 0; n < 4; ++n)
                    acc[m][n] = __builtin_amdgcn_mfma_f32_16x16x32_bf16(
                        ax[m], bx[n], acc[m][n], 0, 0, 0);
        }
    }
    // ---- fused epilogue ----
    const int head = blockIdx.y * 2 + wc;        // wave's head
    float asf[4], adf[4];
#pragma unroll
    for (int n = 0; n < 4; ++n) {
        asf[n] = a_s[head * 64 + n * 16 + (lane & 15)];
        adf[n] = a_d[head * 64 + n * 16 + (lane & 15)];
    }
    const int crow = row0 + wr * 64;
#pragma unroll
    for (int m = 0; m < 4; ++m) {
#pragma unroll
        for (int r = 0; r < 4; ++r) {
            float ss = 0.f, sd = 0.f;
#pragma unroll
            for (int n = 0; n < 4; ++n) {
                float v = acc[m][n][r];
                ss = fmaf(v, asf[n], ss);
                sd = fmaf(v, adf[n], sd);
            }
#pragma unroll
            for (int msk = 1; msk < 16; msk <<= 1) {
                ss += __shfl_xor(ss, msk, 64);
                sd += __shfl_xor(sd, msk, 64);
            }
            int rg = crow + m * 16 + (lane >> 4) * 4 + r;
            if (rg < N) {
                if ((lane & 15) == 0) {
                    f32x2 pv; pv.x = __expf(ss); pv.y = __expf(NEG_SLOPE * ss);
                    *reinterpret_cast<f32x2*>(&pq[(size_t)rg * 8 + head * 2]) = pv;
                    al_d[rg * 4 + head] = sd;
                }
#pragma unroll
                for (int n = 0; n < 4; ++n) {
                    int w8 = __builtin_amdgcn_cvt_pk_fp8_f32(acc[m][n][r], acc[m][n][r], 0, false);
                    h8b[(size_t)rg * 256 + head * 64 + n * 16 + (lane & 15)] =
                        (unsigned char)(w8 & 0xFF);
                }
            }
        }
    }
}

// ================= bucketed CSR build (128-dst buckets) =====================
__global__ __launch_bounds__(256) void bucket_hist(
        const int* __restrict__ dstI, int E, int Etot,
        int* __restrict__ bcnt, int NB) {
    __shared__ int h[512];
    int t = threadIdx.x;
    for (int j = t; j < NB; j += 256) h[j] = 0;
    __syncthreads();
    int base = blockIdx.x * 2048;
#pragma unroll
    for (int j = 0; j < 8; ++j) {
        int e = base + j * 256 + t;
        if (e < Etot) {
            int d = (e < E) ? dstI[e] : (e - E);
            atomicAdd(&h[d >> 7], 1);
        }
    }
    __syncthreads();
    for (int j = t; j < NB; j += 256)
        if (h[j]) atomicAdd(&bcnt[j], h[j]);
}

__global__ __launch_bounds__(512) void bucket_scan(
        const int* __restrict__ bcnt, int NB, int Etot,
        int* __restrict__ bbase, int* __restrict__ bcursor,
        int* __restrict__ rp, int N) {
    __shared__ int a[512], b[512];
    int t = threadIdx.x;
    a[t] = (t < NB) ? bcnt[t] : 0;
    __syncthreads();
    int* s = a; int* d = b;
    for (int ofs = 1; ofs < 512; ofs <<= 1) {
        d[t] = (t >= ofs) ? s[t] + s[t - ofs] : s[t];
        __syncthreads();
        int* tmp = s; s = d; d = tmp;
    }
    int excl = (t == 0) ? 0 : s[t - 1];
    if (t < NB) { bbase[t] = excl; bcursor[t] = excl; }
    if (t == NB) bbase[NB] = Etot;
    if (t == 0) rp[N] = Etot;
}

#define EPB 16
__global__ __launch_bounds__(256) void bin_scatter(
        const int* __restrict__ srcI, const int* __restrict__ dstI,
        int E, int Etot, int* __restrict__ bcursor,
        unsigned* __restrict__ binned, int NB) {
    __shared__ int cnt[512];
    int t = threadIdx.x;
    for (int j = t; j < NB; j += 256) cnt[j] = 0;
    __syncthreads();
    int base_e = blockIdx.x * (256 * EPB) + t;
    unsigned rec[EPB];
    int bkt[EPB];
#pragma unroll
    for (int j = 0; j < EPB; ++j) {
        int e = base_e + j * 256;
        bkt[j] = -1;
        if (e < Etot) {
            int s = (e < E) ? srcI[e] : (e - E);
            int d = (e < E) ? dstI[e] : (e - E);
            bkt[j] = d >> 7;
            rec[j] = ((unsigned)(d & 127) << 16) | (unsigned)s;
            atomicAdd(&cnt[bkt[j]], 1);
        }
    }
    __syncthreads();
    for (int j = t; j < NB; j += 256) {
        int c = cnt[j];
        cnt[j] = c ? atomicAdd(&bcursor[j], c) : 0;
    }
    __syncthreads();
#pragma unroll
    for (int j = 0; j < EPB; ++j)
        if (bkt[j] >= 0) {
            int pos = atomicAdd(&cnt[bkt[j]], 1);
            binned[pos] = rec[j];
        }
}

__global__ __launch_bounds__(256) void bucket_csr(
        const unsigned* __restrict__ binned, const int* __restrict__ bbase,
        int N, int* __restrict__ rp, u16* __restrict__ srcp) {
    int b = blockIdx.x;
    int start = bbase[b];
    int cnt = bbase[b + 1] - start;
    __shared__ int dcnt[128];
    __shared__ int dofs[128];
    __shared__ int wtot;
    int t = threadIdx.x;
    if (t < 128) dcnt[t] = 0;
    __syncthreads();
    for (int i = t; i < cnt; i += 256)
        atomicAdd(&dcnt[binned[start + i] >> 16], 1);
    __syncthreads();
    int v = 0, x = 0;
    if (t < 128) {
        v = dcnt[t];
        x = v;
#pragma unroll
        for (int ofs = 1; ofs < 64; ofs <<= 1) {
            int u = __shfl_up(x, ofs, 64);
            if ((t & 63) >= ofs) x += u;
        }
    }
    if (t == 63) wtot = x;
    __syncthreads();
    if (t >= 64 && t < 128) x += wtot;
    if (t < 128) {
        int abs0 = start + (x - v);
        int d = b * 128 + t;
        if (d < N) rp[d] = abs0;
        dofs[t] = abs0;
    }
    __syncthreads();
    for (int i = t; i < cnt; i += 256) {
        unsigned rec = binned[start + i];
        int pos = atomicAdd(&dofs[rec >> 16], 1);
        srcp[pos] = (u16)(rec & 0xFFFFu);
    }
}

// ----- single-pass fused aggregate: half-wave per edge, fp8 gather ---------
template<bool ELU>
__global__ __launch_bounds__(256) void gat_fused_h4(
        const unsigned* __restrict__ h8, const float* __restrict__ pq,
        const float* __restrict__ al_d, const float* __restrict__ b,
        const int* __restrict__ rp, const u16* __restrict__ srcp,
        int N, u16* __restrict__ out) {
    const int lane = threadIdx.x & 63;
    const int hlf = lane >> 5;          // half owns alternating edges
    const int l = lane & 31;            // lane covers channels [8l, 8l+8)
    const int head = l >> 3;
    int w = (blockIdx.x * blockDim.x + threadIdx.x) >> 6;
    int nw = (gridDim.x * blockDim.x) >> 6;
    for (int d = w; d < N; d += nw) {
        int start = rp[d], end = rp[d + 1];
        float ald = al_d[d * 4 + head];
        float pb = __expf(ald);
        float qb = __expf(NEG_SLOPE * ald);
        float a0 = 0, a1 = 0, a2 = 0, a3 = 0, a4 = 0, a5 = 0, a6 = 0, a7 = 0, L = 0;

#define EDGE1(S) {                                                              \
        unsigned s_ = (S);                                                      \
        uint2 hv_ = *reinterpret_cast<const uint2*>(&h8[s_ * 64u + (unsigned)l * 2u]); \
        f32x2 pv_ = *reinterpret_cast<const f32x2*>(&pq[s_ * 8u + (unsigned)head * 2u]); \
        float t_ = pv_.x * pb;                                                  \
        float e_ = (t_ > 1.f) ? t_ : pv_.y * qb;                                \
        L += e_;                                                                \
        f32x2 p0_ = __builtin_amdgcn_cvt_pk_f32_fp8((int)hv_.x, false);         \
        f32x2 p1_ = __builtin_amdgcn_cvt_pk_f32_fp8((int)hv_.x, true);          \
        f32x2 p2_ = __builtin_amdgcn_cvt_pk_f32_fp8((int)hv_.y, false);         \
        f32x2 p3_ = __builtin_amdgcn_cvt_pk_f32_fp8((int)hv_.y, true);          \
        a0 = fmaf(e_, p0_.x, a0); a1 = fmaf(e_, p0_.y, a1);                     \
        a2 = fmaf(e_, p1_.x, a2); a3 = fmaf(e_, p1_.y, a3);                     \
        a4 = fmaf(e_, p2_.x, a4); a5 = fmaf(e_, p2_.y, a5);                     \
        a6 = fmaf(e_, p3_.x, a6); a7 = fmaf(e_, p3_.y, a7); }

        int i = start;
        int pre = (4 - (i & 3)) & 3;
        if (pre > end - i) pre = end - i;
        for (int k = hlf; k < pre; k += 2) EDGE1(srcp[i + k]);
        i += pre;
        int nb = (end - i) & ~7;
        int stop = i + nb;
        for (int j = i + hlf * 4; j < stop; j += 8) {
            u16x4 sv = *reinterpret_cast<const u16x4*>(&srcp[j]);
            unsigned s4[4] = {sv[0], sv[1], sv[2], sv[3]};
            uint2 hv[4]; f32x2 pv[4];
#pragma unroll
            for (int q = 0; q < 4; ++q) {
                hv[q] = *reinterpret_cast<const uint2*>(&h8[s4[q] * 64u + (unsigned)l * 2u]);
                pv[q] = *reinterpret_cast<const f32x2*>(&pq[s4[q] * 8u + (unsigned)head * 2u]);
            }
#pragma unroll
            for (int q = 0; q < 4; ++q) {
                float t = pv[q].x * pb;
                float e = (t > 1.f) ? t : pv[q].y * qb;
                L += e;
                f32x2 p0 = __builtin_amdgcn_cvt_pk_f32_fp8((int)hv[q].x, false);
                f32x2 p1 = __builtin_amdgcn_cvt_pk_f32_fp8((int)hv[q].x, true);
                f32x2 p2 = __builtin_amdgcn_cvt_pk_f32_fp8((int)hv[q].y, false);
                f32x2 p3 = __builtin_amdgcn_cvt_pk_f32_fp8((int)hv[q].y, true);
                a0 = fmaf(e, p0.x, a0); a1 = fmaf(e, p0.y, a1);
                a2 = fmaf(e, p1.x, a2); a3 = fmaf(e, p1.y, a3);
                a4 = fmaf(e, p2.x, a4); a5 = fmaf(e, p2.y, a5);
                a6 = fmaf(e, p3.x, a6); a7 = fmaf(e, p3.y, a7);
            }
        }
        for (int k = stop + hlf; k < end; k += 2) EDGE1(srcp[k]);
#undef EDGE1

        // combine halves
        a0 += __shfl_xor(a0, 32, 64); a1 += __shfl_xor(a1, 32, 64);
        a2 += __shfl_xor(a2, 32, 64); a3 += __shfl_xor(a3, 32, 64);
        a4 += __shfl_xor(a4, 32, 64); a5 += __shfl_xor(a5, 32, 64);
        a6 += __shfl_xor(a6, 32, 64); a7 += __shfl_xor(a7, 32, 64);
        L += __shfl_xor(L, 32, 64);
        float inv = 1.f / (L + 1e-16f);
        if (hlf == 0) {
            float4 b0 = *reinterpret_cast<const float4*>(&b[l * 8]);
            float4 b1 = *reinterpret_cast<const float4*>(&b[l * 8 + 4]);
            float o0 = fmaf(a0, inv, b0.x), o1 = fmaf(a1, inv, b0.y);
            float o2 = fmaf(a2, inv, b0.z), o3 = fmaf(a3, inv, b0.w);
            float o4 = fmaf(a4, inv, b1.x), o5 = fmaf(a5, inv, b1.y);
            float o6 = fmaf(a6, inv, b1.z), o7 = fmaf(a7, inv, b1.w);
            if (ELU) {
                o0 = (o0 > 0.f) ? o0 : expm1f(o0);
                o1 = (o1 > 0.f) ? o1 : expm1f(o1);
                o2 = (o2 > 0.f) ? o2 : expm1f(o2);
                o3 = (o3 > 0.f) ? o3 : expm1f(o3);
                o4 = (o4 > 0.f) ? o4 : expm1f(o4);
                o5 = (o5 > 0.f) ? o5 : expm1f(o5);
                o6 = (o6 > 0.f) ? o6 : expm1f(o6);
                o7 = (o7 > 0.f) ? o7 : expm1f(o7);
            }
            u16x8 ov;
            ov[0] = f2b(o0); ov[1] = f2b(o1); ov[2] = f2b(o2); ov[3] = f2b(o3);
            ov[4] = f2b(o4); ov[5] = f2b(o5); ov[6] = f2b(o6); ov[7] = f2b(o7);
            *reinterpret_cast<u16x8*>(&out[(size_t)d * 256 + l * 8]) = ov;
        }
    }
}

// ================= layer-3 linear-collapse path =============================
__global__ __launch_bounds__(256) void compute_al3(
        const u16* __restrict__ ob, const float* __restrict__ W3,
        const float* __restrict__ as3, const float* __restrict__ ad3, int N,
        float* __restrict__ pq3, float* __restrict__ al_d) {
    __shared__ float was[256], wad[256];
    {
        int t = threadIdx.x;
        float ss = 0.f, sd = 0.f;
#pragma unroll
        for (int c = 0; c < 10; ++c) {
            float w = W3[t * 10 + c];
            ss = fmaf(w, as3[c], ss);
            sd = fmaf(w, ad3[c], sd);
        }
        was[t] = ss; wad[t] = sd;
    }
    __syncthreads();
    const int lane = threadIdx.x & 63;
    int n = (blockIdx.x * blockDim.x + threadIdx.x) >> 6;
    if (n >= N) return;
    u16x4 hv = *reinterpret_cast<const u16x4*>(&ob[(size_t)n * 256 + lane * 4]);
    float4 ws = *reinterpret_cast<const float4*>(&was[lane * 4]);
    float4 wd = *reinterpret_cast<const float4*>(&wad[lane * 4]);
    float f0 = b2f((u16)hv[0]), f1 = b2f((u16)hv[1]);
    float f2 = b2f((u16)hv[2]), f3 = b2f((u16)hv[3]);
    float ss = f0 * ws.x + f1 * ws.y + f2 * ws.z + f3 * ws.w;
    float sd = f0 * wd.x + f1 * wd.y + f2 * wd.z + f3 * wd.w;
#pragma unroll
    for (int m = 1; m < 64; m <<= 1) {
        ss += __shfl_xor(ss, m, 64);
        sd += __shfl_xor(sd, m, 64);
    }
    if (lane == 0) {
        f32x2 pv; pv.x = __expf(ss); pv.y = __expf(NEG_SLOPE * ss);
        *reinterpret_cast<f32x2*>(&pq3[(size_t)n * 2]) = pv;
        al_d[n] = sd;
    }
}

__global__ __launch_bounds__(256) void l3_edge(
        const float* __restrict__ pq3, const float* __restrict__ al_d,
        const int* __restrict__ rp, const u16* __restrict__ srcp,
        int N, float* __restrict__ wq) {
    const int lane = threadIdx.x & 63;
    int w = (blockIdx.x * blockDim.x + threadIdx.x) >> 6;
    int nw = (gridDim.x * blockDim.x) >> 6;
    for (int d = w; d < N; d += nw) {
        int start = rp[d], end = rp[d + 1];
        float ald = al_d[d];
        float pb = __expf(ald);
        float qb = __expf(NEG_SLOPE * ald);
        float L = 0.f;
        for (int i = start + lane; i < end; i += 64) {
            f32x2 pqv = *reinterpret_cast<const f32x2*>(&pq3[(unsigned)srcp[i] * 2u]);
            float t = pqv.x * pb;
            L += (t > 1.f) ? t : pqv.y * qb;
        }
#pragma unroll
        for (int m = 1; m < 64; m <<= 1) L += __shfl_xor(L, m, 64);
        float inv = 1.f / (L + 1e-16f);
        for (int i = start + lane; i < end; i += 64) {
            unsigned s = srcp[i];
            f32x2 pqv = *reinterpret_cast<const f32x2*>(&pq3[s * 2u]);
            float t = pqv.x * pb;
            float e = (t > 1.f) ? t : pqv.y * qb;
            atomicAdd(&wq[s], e * inv);
        }
    }
}

__global__ __launch_bounds__(256) void wcolsum(const u16* __restrict__ ob,
                                               const float* __restrict__ w, int N,
                                               float* __restrict__ pp) {
    __shared__ float sh[4][256];
    const int lane = threadIdx.x & 63;
    const int wid = threadIdx.x >> 6;
    int wv = (blockIdx.x * blockDim.x + threadIdx.x) >> 6;
    int nw = (gridDim.x * blockDim.x) >> 6;
    float a0 = 0.f, a1 = 0.f, a2 = 0.f, a3 = 0.f;
    for (int n = wv; n < N; n += nw) {
        float wn = w[n];
        u16x4 hv = *reinterpret_cast<const u16x4*>(&ob[(size_t)n * 256 + lane * 4]);
        a0 = fmaf(wn, b2f((u16)hv[0]), a0);
        a1 = fmaf(wn, b2f((u16)hv[1]), a1);
        a2 = fmaf(wn, b2f((u16)hv[2]), a2);
        a3 = fmaf(wn, b2f((u16)hv[3]), a3);
    }
    sh[wid][lane * 4 + 0] = a0;
    sh[wid][lane * 4 + 1] = a1;
    sh[wid][lane * 4 + 2] = a2;
    sh[wid][lane * 4 + 3] = a3;
    __syncthreads();
    int t = threadIdx.x;
    float s = sh[0][t] + sh[1][t] + sh[2][t] + sh[3][t];
    atomicAdd(&pp[t], s);
}

__global__ void final_out(const float* __restrict__ pp, const float* __restrict__ W3,
                          const float* __restrict__ b3, int N, float* __restrict__ out) {
    __shared__ float acc[10];
    int t = threadIdx.x;  // 256
    if (t < 10) acc[t] = 0.f;
    __syncthreads();
    float pk = pp[t] / (float)N;
#pragma unroll
    for (int c = 0; c < 10; ++c) atomicAdd(&acc[c], pk * W3[t * 10 + c]);
    __syncthreads();
    if (t == 0) {
        float p[10];
        float mx = -INFINITY;
        for (int c = 0; c < 10; ++c) {
            p[c] = acc[c] + b3[c];
            mx = fmaxf(mx, p[c]);
        }
        float s = 0.f;
        for (int c = 0; c < 10; ++c) s += expf(p[c] - mx);
        float ls = logf(s);
        for (int c = 0; c < 10; ++c) out[c] = p[c] - mx - ls;
    }
}

extern "C" void kernel_launch(void* const* d_in, const int* in_sizes, int n_in,
                              void* d_out, int out_size, void* d_ws, size_t ws_size,
                              hipStream_t stream) {
    const float* x   = (const float*)d_in[0];
    const int*   ei  = (const int*)d_in[1];
    const float* W1  = (const float*)d_in[2];
    const float* as1 = (const float*)d_in[3];
    const float* ad1 = (const float*)d_in[4];
    const float* b1  = (const float*)d_in[5];
    const float* W2  = (const float*)d_in[6];
    const float* as2 = (const float*)d_in[7];
    const float* ad2 = (const float*)d_in[8];
    const float* b2  = (const float*)d_in[9];
    const float* W3  = (const float*)d_in[10];
    const float* as3 = (const float*)d_in[11];
    const float* ad3 = (const float*)d_in[12];
    const float* b3  = (const float*)d_in[13];
    float* out = (float*)d_out;

    const int N = in_sizes[0] / 128;   // 50000
    const int E = in_sizes[1] / 2;     // 800000
    const int Etot = E + N;
    const int NB = (N + 127) >> 7;     // 128-dst buckets
    const int* srcI = ei;
    const int* dstI = ei + E;

    char* base = (char*)d_ws;
    size_t off = 0;
    auto alloc = [&](size_t bytes) {
        void* p = base + off;
        off = (off + bytes + 255) & ~(size_t)255;
        return p;
    };
    u16* x_bf  = (u16*)alloc((size_t)N * 128 * 2);
    unsigned* h8 = (unsigned*)alloc((size_t)N * 256);
    u16* oa_bf = (u16*)alloc((size_t)N * 256 * 2);
    u16* ob_bf = (u16*)alloc((size_t)N * 256 * 2);
    u16* w1t   = (u16*)alloc(256 * 128 * 2);
    u16* w2t   = (u16*)alloc(256 * 256 * 2);
    float* pq   = (float*)alloc((size_t)N * 8 * 4);   // [n][4] float2
    float* al_d = (float*)alloc((size_t)N * 4 * 4);
    float* pq3  = (float*)alloc((size_t)N * 2 * 4);   // [n] float2
    // contiguous zero region: bcnt | wq | pp
    int* bcnt   = (int*)alloc(512 * 4);
    float* wq   = (float*)alloc((size_t)N * 4);
    float* pp   = (float*)alloc(256 * 4);
    int* rp     = (int*)alloc((size_t)(N + 1) * 4);
    int* bbase  = (int*)alloc(512 * 4);
    int* bcursor = (int*)alloc(512 * 4);
    unsigned* binned = (unsigned*)alloc((size_t)Etot * 4);
    u16* srcp   = (u16*)alloc((size_t)Etot * 2);

    // ---- prep: cast x, transpose weights, zero scratch (one dispatch) ----
    const int n4 = N * 128 / 4;
    const int B0 = (n4 + 255) / 256;
    const int B1 = B0 + (128 * 256 + 255) / 256;
    const int B2 = B1 + (256 * 256 + 255) / 256;
    int span = (int)(((char*)(pp + 256) - (char*)bcnt) / 4);
    const int B3 = B2 + (span + 255) / 256;
    prep<<<B3, 256, 0, stream>>>(x, x_bf, n4, W1, w1t, W2, w2t,
                                 bcnt, span, B0, B1, B2);

    // ---- bucketed CSR build ----
    bucket_hist<<<(Etot + 2047) / 2048, 256, 0, stream>>>(dstI, E, Etot, bcnt, NB);
    bucket_scan<<<1, 512, 0, stream>>>(bcnt, NB, Etot, bbase, bcursor, rp, N);
    bin_scatter<<<(Etot + 256 * EPB - 1) / (256 * EPB), 256, 0, stream>>>(
        srcI, dstI, E, Etot, bcursor, binned, NB);
    bucket_csr<<<NB, 256, 0, stream>>>(binned, bbase, N, rp, srcp);

    const int FUSED_BLOCKS = (N + 3) / 4;
    const int GX = (N + 127) / 128;

    // ---- layer 1: x_bf[N,128] -> oa_bf[N,256], ELU ----
    {
        dim3 g(GX, 2);
        gemm_mfma_fused<<<g, 256, 0, stream>>>(x_bf, w1t, N, 128, as1, ad1,
                                               (unsigned char*)h8, pq, al_d);
        gat_fused_h4<true><<<FUSED_BLOCKS, 256, 0, stream>>>(
            h8, pq, al_d, b1, rp, srcp, N, oa_bf);
    }
    // ---- layer 2: oa_bf -> ob_bf, ELU ----
    {
        dim3 g(GX, 2);
        gemm_mfma_fused<<<g, 256, 0, stream>>>(oa_bf, w2t, N, 256, as2, ad2,
                                               (unsigned char*)h8, pq, al_d);
        gat_fused_h4<true><<<FUSED_BLOCKS, 256, 0, stream>>>(
            h8, pq, al_d, b2, rp, srcp, N, ob_bf);
    }
    // ---- layer 3 (linear-collapsed): pooled = (1/N * sum_s w_s ob_s) @ W3 + b3
    {
        compute_al3<<<(N + 3) / 4, 256, 0, stream>>>(ob_bf, W3, as3, ad3, N, pq3, al_d);
        l3_edge<<<(N + 3) / 4, 256, 0, stream>>>(pq3, al_d, rp, srcp, N, wq);
        wcolsum<<<1024, 256, 0, stream>>>(ob_bf, wq, N, pp);
        final_out<<<1, 256, 0, stream>>>(pp, W3, b3, N, out);
    }
}

// Round 16
// 319.703 us; speedup vs baseline: 1.4142x; 1.0016x over previous
//
#include <hip/hip_runtime.h>
#include <math.h>

#define NEG_SLOPE 0.2f

typedef __attribute__((ext_vector_type(8))) short bf16x8;
typedef __attribute__((ext_vector_type(4))) float f32x4;
typedef __attribute__((ext_vector_type(2))) float f32x2;
typedef unsigned short u16;
typedef __attribute__((ext_vector_type(4))) unsigned short u16x4;
typedef __attribute__((ext_vector_type(8))) unsigned short u16x8;

__device__ __forceinline__ float b2f(u16 u) {
    return __uint_as_float(((unsigned)u) << 16);
}
__device__ __forceinline__ u16 f2b(float f) {
    unsigned u = __float_as_uint(f);
    unsigned r = (u + 0x7fffu + ((u >> 16) & 1u)) >> 16;
    return (u16)r;
}

// ---------------- fused prep: cast x, transpose W1/W2, zero scratch --------
__global__ void prep(const float* __restrict__ x, u16* __restrict__ x_bf, int n4,
                     const float* __restrict__ W1, u16* __restrict__ w1t,
                     const float* __restrict__ W2, u16* __restrict__ w2t,
                     int* __restrict__ zero_base, int nzero,
                     int B0, int B1, int B2) {
    int blk = blockIdx.x;
    if (blk < B0) {
        int i = blk * 256 + threadIdx.x;
        if (i < n4) {
            float4 v = *reinterpret_cast<const float4*>(&x[i * 4]);
            u16x4 o;
            o[0] = f2b(v.x); o[1] = f2b(v.y); o[2] = f2b(v.z); o[3] = f2b(v.w);
            *reinterpret_cast<u16x4*>(&x_bf[i * 4]) = o;
        }
    } else if (blk < B1) {
        int i = (blk - B0) * 256 + threadIdx.x;  // [M][K], K=128, M=256
        if (i < 128 * 256) {
            int m = i >> 7, k = i & 127;
            w1t[i] = f2b(W1[(size_t)k * 256 + m]);
        }
    } else if (blk < B2) {
        int i = (blk - B1) * 256 + threadIdx.x;  // K=256, M=256
        if (i < 256 * 256) {
            int m = i >> 8, k = i & 255;
            w2t[i] = f2b(W2[(size_t)k * 256 + m]);
        }
    } else {
        int i = (blk - B2) * 256 + threadIdx.x;
        if (i < nzero) zero_base[i] = 0;
    }
}

// ---- MFMA GEMM (M=256) with fused epilogue: fp8 h, pq=(e^al_s,e^.2al_s), al_d
// Each wave owns 64 rows x 64 cols = one head's full channel range.
__global__ __launch_bounds__(256) void gemm_mfma_fused(
        const u16* __restrict__ A, const u16* __restrict__ Bt,
        int N, int K,
        const float* __restrict__ a_s, const float* __restrict__ a_d,
        unsigned char* __restrict__ h8b, float* __restrict__ pq,
        float* __restrict__ al_d) {
    __shared__ u16 As[128 * 64];
    __shared__ u16 Bs[128 * 64];
    const int tid = threadIdx.x;
    const int lane = tid & 63;
    const int wid = tid >> 6;
    const int wr = wid >> 1, wc = wid & 1;
    const int row0 = blockIdx.x * 128;
    const int col0 = blockIdx.y * 128;
    f32x4 acc[4][4] = {};
    for (int k0 = 0; k0 < K; k0 += 64) {
        if (k0) __syncthreads();
#pragma unroll
        for (int i = 0; i < 4; ++i) {
            int chunk = i * 256 + tid;
            int row = chunk >> 3;
            int slot = chunk & 7;
            int grow = row0 + row; if (grow >= N) grow = N - 1;
            bf16x8 v = *reinterpret_cast<const bf16x8*>(&A[(size_t)grow * K + k0 + slot * 8]);
            int swz = (chunk & ~7) | (slot ^ (row & 7));
            *reinterpret_cast<bf16x8*>(&As[swz * 8]) = v;
        }
#pragma unroll
        for (int i = 0; i < 4; ++i) {
            int chunk = i * 256 + tid;
            int row = chunk >> 3;
            int slot = chunk & 7;
            int gcol = col0 + row;
            bf16x8 v = *reinterpret_cast<const bf16x8*>(&Bt[(size_t)gcol * K + k0 + slot * 8]);
            int swz = (chunk & ~7) | (slot ^ (row & 7));
            *reinterpret_cast<bf16x8*>(&Bs[swz * 8]) = v;
        }
        __syncthreads();
#pragma unroll
        for (int kk = 0; kk < 2; ++kk) {
            bf16x8 ax[4], bx[4];
#pragma unroll
            for (int m = 0; m < 4; ++m) {
                int row = wr * 64 + m * 16 + (lane & 15);
                int slot = kk * 4 + (lane >> 4);
                ax[m] = *reinterpret_cast<const bf16x8*>(&As[(row * 8 + (slot ^ (row & 7))) * 8]);
            }
#pragma unroll
            for (int n = 0; n < 4; ++n) {
                int row = wc * 64 + n * 16 + (lane & 15);
                int slot = kk * 4 + (lane >> 4);
                bx[n] = *reinterpret_cast<const bf16x8*>(&Bs[(row * 8 + (slot ^ (row & 7))) * 8]);
            }
#pragma unroll
            for (int m = 0; m < 4; ++m)
#pragma unroll
                for (int n = 0; n < 4; ++n)
                    acc[m][n] = __builtin_amdgcn_mfma_f32_16x16x32_bf16(
                        ax[m], bx[n], acc[m][n], 0, 0, 0);
        }
    }
    // ---- fused epilogue ----
    const int head = blockIdx.y * 2 + wc;        // wave's head
    float asf[4], adf[4];
#pragma unroll
    for (int n = 0; n < 4; ++n) {
        asf[n] = a_s[head * 64 + n * 16 + (lane & 15)];
        adf[n] = a_d[head * 64 + n * 16 + (lane & 15)];
    }
    const int crow = row0 + wr * 64;
#pragma unroll
    for (int m = 0; m < 4; ++m) {
#pragma unroll
        for (int r = 0; r < 4; ++r) {
            float ss = 0.f, sd = 0.f;
#pragma unroll
            for (int n = 0; n < 4; ++n) {
                float v = acc[m][n][r];
                ss = fmaf(v, asf[n], ss);
                sd = fmaf(v, adf[n], sd);
            }
#pragma unroll
            for (int msk = 1; msk < 16; msk <<= 1) {
                ss += __shfl_xor(ss, msk, 64);
                sd += __shfl_xor(sd, msk, 64);
            }
            int rg = crow + m * 16 + (lane >> 4) * 4 + r;
            if (rg < N) {
                if ((lane & 15) == 0) {
                    f32x2 pv; pv.x = __expf(ss); pv.y = __expf(NEG_SLOPE * ss);
                    *reinterpret_cast<f32x2*>(&pq[(size_t)rg * 8 + head * 2]) = pv;
                    al_d[rg * 4 + head] = sd;
                }
#pragma unroll
                for (int n = 0; n < 4; ++n) {
                    int w8 = __builtin_amdgcn_cvt_pk_fp8_f32(acc[m][n][r], acc[m][n][r], 0, false);
                    h8b[(size_t)rg * 256 + head * 64 + n * 16 + (lane & 15)] =
                        (unsigned char)(w8 & 0xFF);
                }
            }
        }
    }
}

// ================= bucketed CSR build (128-dst buckets) =====================
__global__ __launch_bounds__(256) void bucket_hist(
        const int* __restrict__ dstI, int E, int Etot,
        int* __restrict__ bcnt, int NB) {
    __shared__ int h[512];
    int t = threadIdx.x;
    for (int j = t; j < NB; j += 256) h[j] = 0;
    __syncthreads();
    int base = blockIdx.x * 2048;
#pragma unroll
    for (int j = 0; j < 8; ++j) {
        int e = base + j * 256 + t;
        if (e < Etot) {
            int d = (e < E) ? dstI[e] : (e - E);
            atomicAdd(&h[d >> 7], 1);
        }
    }
    __syncthreads();
    for (int j = t; j < NB; j += 256)
        if (h[j]) atomicAdd(&bcnt[j], h[j]);
}

__global__ __launch_bounds__(512) void bucket_scan(
        const int* __restrict__ bcnt, int NB, int Etot,
        int* __restrict__ bbase, int* __restrict__ bcursor,
        int* __restrict__ rp, int N) {
    __shared__ int a[512], b[512];
    int t = threadIdx.x;
    a[t] = (t < NB) ? bcnt[t] : 0;
    __syncthreads();
    int* s = a; int* d = b;
    for (int ofs = 1; ofs < 512; ofs <<= 1) {
        d[t] = (t >= ofs) ? s[t] + s[t - ofs] : s[t];
        __syncthreads();
        int* tmp = s; s = d; d = tmp;
    }
    int excl = (t == 0) ? 0 : s[t - 1];
    if (t < NB) { bbase[t] = excl; bcursor[t] = excl; }
    if (t == NB) bbase[NB] = Etot;
    if (t == 0) rp[N] = Etot;
}

#define EPB 16
__global__ __launch_bounds__(256) void bin_scatter(
        const int* __restrict__ srcI, const int* __restrict__ dstI,
        int E, int Etot, int* __restrict__ bcursor,
        unsigned* __restrict__ binned, int NB) {
    __shared__ int cnt[512];
    int t = threadIdx.x;
    for (int j = t; j < NB; j += 256) cnt[j] = 0;
    __syncthreads();
    int base_e = blockIdx.x * (256 * EPB) + t;
    unsigned rec[EPB];
    int bkt[EPB];
#pragma unroll
    for (int j = 0; j < EPB; ++j) {
        int e = base_e + j * 256;
        bkt[j] = -1;
        if (e < Etot) {
            int s = (e < E) ? srcI[e] : (e - E);
            int d = (e < E) ? dstI[e] : (e - E);
            bkt[j] = d >> 7;
            rec[j] = ((unsigned)(d & 127) << 16) | (unsigned)s;
            atomicAdd(&cnt[bkt[j]], 1);
        }
    }
    __syncthreads();
    for (int j = t; j < NB; j += 256) {
        int c = cnt[j];
        cnt[j] = c ? atomicAdd(&bcursor[j], c) : 0;
    }
    __syncthreads();
#pragma unroll
    for (int j = 0; j < EPB; ++j)
        if (bkt[j] >= 0) {
            int pos = atomicAdd(&cnt[bkt[j]], 1);
            binned[pos] = rec[j];
        }
}

__global__ __launch_bounds__(256) void bucket_csr(
        const unsigned* __restrict__ binned, const int* __restrict__ bbase,
        int N, int* __restrict__ rp, u16* __restrict__ srcp) {
    int b = blockIdx.x;
    int start = bbase[b];
    int cnt = bbase[b + 1] - start;
    __shared__ int dcnt[128];
    __shared__ int dofs[128];
    __shared__ int wtot;
    int t = threadIdx.x;
    if (t < 128) dcnt[t] = 0;
    __syncthreads();
    for (int i = t; i < cnt; i += 256)
        atomicAdd(&dcnt[binned[start + i] >> 16], 1);
    __syncthreads();
    int v = 0, x = 0;
    if (t < 128) {
        v = dcnt[t];
        x = v;
#pragma unroll
        for (int ofs = 1; ofs < 64; ofs <<= 1) {
            int u = __shfl_up(x, ofs, 64);
            if ((t & 63) >= ofs) x += u;
        }
    }
    if (t == 63) wtot = x;
    __syncthreads();
    if (t >= 64 && t < 128) x += wtot;
    if (t < 128) {
        int abs0 = start + (x - v);
        int d = b * 128 + t;
        if (d < N) rp[d] = abs0;
        dofs[t] = abs0;
    }
    __syncthreads();
    for (int i = t; i < cnt; i += 256) {
        unsigned rec = binned[start + i];
        int pos = atomicAdd(&dofs[rec >> 16], 1);
        srcp[pos] = (u16)(rec & 0xFFFFu);
    }
}

// ----- single-pass fused aggregate: half-wave per edge, fp8 gather ---------
template<bool ELU>
__global__ __launch_bounds__(256) void gat_fused_h4(
        const unsigned* __restrict__ h8, const float* __restrict__ pq,
        const float* __restrict__ al_d, const float* __restrict__ b,
        const int* __restrict__ rp, const u16* __restrict__ srcp,
        int N, u16* __restrict__ out) {
    const int lane = threadIdx.x & 63;
    const int hlf = lane >> 5;          // half owns alternating edges
    const int l = lane & 31;            // lane covers channels [8l, 8l+8)
    const int head = l >> 3;
    int w = (blockIdx.x * blockDim.x + threadIdx.x) >> 6;
    int nw = (gridDim.x * blockDim.x) >> 6;
    for (int d = w; d < N; d += nw) {
        int start = rp[d], end = rp[d + 1];
        float ald = al_d[d * 4 + head];
        float pb = __expf(ald);
        float qb = __expf(NEG_SLOPE * ald);
        float a0 = 0, a1 = 0, a2 = 0, a3 = 0, a4 = 0, a5 = 0, a6 = 0, a7 = 0, L = 0;

#define EDGE1(S) {                                                              \
        unsigned s_ = (S);                                                      \
        uint2 hv_ = *reinterpret_cast<const uint2*>(&h8[s_ * 64u + (unsigned)l * 2u]); \
        f32x2 pv_ = *reinterpret_cast<const f32x2*>(&pq[s_ * 8u + (unsigned)head * 2u]); \
        float t_ = pv_.x * pb;                                                  \
        float e_ = (t_ > 1.f) ? t_ : pv_.y * qb;                                \
        L += e_;                                                                \
        f32x2 p0_ = __builtin_amdgcn_cvt_pk_f32_fp8((int)hv_.x, false);         \
        f32x2 p1_ = __builtin_amdgcn_cvt_pk_f32_fp8((int)hv_.x, true);          \
        f32x2 p2_ = __builtin_amdgcn_cvt_pk_f32_fp8((int)hv_.y, false);         \
        f32x2 p3_ = __builtin_amdgcn_cvt_pk_f32_fp8((int)hv_.y, true);          \
        a0 = fmaf(e_, p0_.x, a0); a1 = fmaf(e_, p0_.y, a1);                     \
        a2 = fmaf(e_, p1_.x, a2); a3 = fmaf(e_, p1_.y, a3);                     \
        a4 = fmaf(e_, p2_.x, a4); a5 = fmaf(e_, p2_.y, a5);                     \
        a6 = fmaf(e_, p3_.x, a6); a7 = fmaf(e_, p3_.y, a7); }

        int i = start;
        int pre = (4 - (i & 3)) & 3;
        if (pre > end - i) pre = end - i;
        for (int k = hlf; k < pre; k += 2) EDGE1(srcp[i + k]);
        i += pre;
        int nb = (end - i) & ~7;
        int stop = i + nb;
        for (int j = i + hlf * 4; j < stop; j += 8) {
            u16x4 sv = *reinterpret_cast<const u16x4*>(&srcp[j]);
            unsigned s4[4] = {sv[0], sv[1], sv[2], sv[3]};
            uint2 hv[4]; f32x2 pv[4];
#pragma unroll
            for (int q = 0; q < 4; ++q) {
                hv[q] = *reinterpret_cast<const uint2*>(&h8[s4[q] * 64u + (unsigned)l * 2u]);
                pv[q] = *reinterpret_cast<const f32x2*>(&pq[s4[q] * 8u + (unsigned)head * 2u]);
            }
#pragma unroll
            for (int q = 0; q < 4; ++q) {
                float t = pv[q].x * pb;
                float e = (t > 1.f) ? t : pv[q].y * qb;
                L += e;
                f32x2 p0 = __builtin_amdgcn_cvt_pk_f32_fp8((int)hv[q].x, false);
                f32x2 p1 = __builtin_amdgcn_cvt_pk_f32_fp8((int)hv[q].x, true);
                f32x2 p2 = __builtin_amdgcn_cvt_pk_f32_fp8((int)hv[q].y, false);
                f32x2 p3 = __builtin_amdgcn_cvt_pk_f32_fp8((int)hv[q].y, true);
                a0 = fmaf(e, p0.x, a0); a1 = fmaf(e, p0.y, a1);
                a2 = fmaf(e, p1.x, a2); a3 = fmaf(e, p1.y, a3);
                a4 = fmaf(e, p2.x, a4); a5 = fmaf(e, p2.y, a5);
                a6 = fmaf(e, p3.x, a6); a7 = fmaf(e, p3.y, a7);
            }
        }
        for (int k = stop + hlf; k < end; k += 2) EDGE1(srcp[k]);
#undef EDGE1

        // combine halves
        a0 += __shfl_xor(a0, 32, 64); a1 += __shfl_xor(a1, 32, 64);
        a2 += __shfl_xor(a2, 32, 64); a3 += __shfl_xor(a3, 32, 64);
        a4 += __shfl_xor(a4, 32, 64); a5 += __shfl_xor(a5, 32, 64);
        a6 += __shfl_xor(a6, 32, 64); a7 += __shfl_xor(a7, 32, 64);
        L += __shfl_xor(L, 32, 64);
        float inv = 1.f / (L + 1e-16f);
        if (hlf == 0) {
            float4 b0 = *reinterpret_cast<const float4*>(&b[l * 8]);
            float4 b1 = *reinterpret_cast<const float4*>(&b[l * 8 + 4]);
            float o0 = fmaf(a0, inv, b0.x), o1 = fmaf(a1, inv, b0.y);
            float o2 = fmaf(a2, inv, b0.z), o3 = fmaf(a3, inv, b0.w);
            float o4 = fmaf(a4, inv, b1.x), o5 = fmaf(a5, inv, b1.y);
            float o6 = fmaf(a6, inv, b1.z), o7 = fmaf(a7, inv, b1.w);
            if (ELU) {
                o0 = (o0 > 0.f) ? o0 : expm1f(o0);
                o1 = (o1 > 0.f) ? o1 : expm1f(o1);
                o2 = (o2 > 0.f) ? o2 : expm1f(o2);
                o3 = (o3 > 0.f) ? o3 : expm1f(o3);
                o4 = (o4 > 0.f) ? o4 : expm1f(o4);
                o5 = (o5 > 0.f) ? o5 : expm1f(o5);
                o6 = (o6 > 0.f) ? o6 : expm1f(o6);
                o7 = (o7 > 0.f) ? o7 : expm1f(o7);
            }
            u16x8 ov;
            ov[0] = f2b(o0); ov[1] = f2b(o1); ov[2] = f2b(o2); ov[3] = f2b(o3);
            ov[4] = f2b(o4); ov[5] = f2b(o5); ov[6] = f2b(o6); ov[7] = f2b(o7);
            *reinterpret_cast<u16x8*>(&out[(size_t)d * 256 + l * 8]) = ov;
        }
    }
}

// ================= layer-3 linear-collapse path =============================
__global__ __launch_bounds__(256) void compute_al3(
        const u16* __restrict__ ob, const float* __restrict__ W3,
        const float* __restrict__ as3, const float* __restrict__ ad3, int N,
        float* __restrict__ pq3, float* __restrict__ al_d) {
    __shared__ float was[256], wad[256];
    {
        int t = threadIdx.x;
        float ss = 0.f, sd = 0.f;
#pragma unroll
        for (int c = 0; c < 10; ++c) {
            float w = W3[t * 10 + c];
            ss = fmaf(w, as3[c], ss);
            sd = fmaf(w, ad3[c], sd);
        }
        was[t] = ss; wad[t] = sd;
    }
    __syncthreads();
    const int lane = threadIdx.x & 63;
    int n = (blockIdx.x * blockDim.x + threadIdx.x) >> 6;
    if (n >= N) return;
    u16x4 hv = *reinterpret_cast<const u16x4*>(&ob[(size_t)n * 256 + lane * 4]);
    float4 ws = *reinterpret_cast<const float4*>(&was[lane * 4]);
    float4 wd = *reinterpret_cast<const float4*>(&wad[lane * 4]);
    float f0 = b2f((u16)hv[0]), f1 = b2f((u16)hv[1]);
    float f2 = b2f((u16)hv[2]), f3 = b2f((u16)hv[3]);
    float ss = f0 * ws.x + f1 * ws.y + f2 * ws.z + f3 * ws.w;
    float sd = f0 * wd.x + f1 * wd.y + f2 * wd.z + f3 * wd.w;
#pragma unroll
    for (int m = 1; m < 64; m <<= 1) {
        ss += __shfl_xor(ss, m, 64);
        sd += __shfl_xor(sd, m, 64);
    }
    if (lane == 0) {
        f32x2 pv; pv.x = __expf(ss); pv.y = __expf(NEG_SLOPE * ss);
        *reinterpret_cast<f32x2*>(&pq3[(size_t)n * 2]) = pv;
        al_d[n] = sd;
    }
}

__global__ __launch_bounds__(256) void l3_edge(
        const float* __restrict__ pq3, const float* __restrict__ al_d,
        const int* __restrict__ rp, const u16* __restrict__ srcp,
        int N, float* __restrict__ wq) {
    const int lane = threadIdx.x & 63;
    int w = (blockIdx.x * blockDim.x + threadIdx.x) >> 6;
    int nw = (gridDim.x * blockDim.x) >> 6;
    for (int d = w; d < N; d += nw) {
        int start = rp[d], end = rp[d + 1];
        float ald = al_d[d];
        float pb = __expf(ald);
        float qb = __expf(NEG_SLOPE * ald);
        float L = 0.f;
        for (int i = start + lane; i < end; i += 64) {
            f32x2 pqv = *reinterpret_cast<const f32x2*>(&pq3[(unsigned)srcp[i] * 2u]);
            float t = pqv.x * pb;
            L += (t > 1.f) ? t : pqv.y * qb;
        }
#pragma unroll
        for (int m = 1; m < 64; m <<= 1) L += __shfl_xor(L, m, 64);
        float inv = 1.f / (L + 1e-16f);
        for (int i = start + lane; i < end; i += 64) {
            unsigned s = srcp[i];
            f32x2 pqv = *reinterpret_cast<const f32x2*>(&pq3[s * 2u]);
            float t = pqv.x * pb;
            float e = (t > 1.f) ? t : pqv.y * qb;
            atomicAdd(&wq[s], e * inv);
        }
    }
}

__global__ __launch_bounds__(256) void wcolsum(const u16* __restrict__ ob,
                                               const float* __restrict__ w, int N,
                                               float* __restrict__ pp) {
    __shared__ float sh[4][256];
    const int lane = threadIdx.x & 63;
    const int wid = threadIdx.x >> 6;
    int wv = (blockIdx.x * blockDim.x + threadIdx.x) >> 6;
    int nw = (gridDim.x * blockDim.x) >> 6;
    float a0 = 0.f, a1 = 0.f, a2 = 0.f, a3 = 0.f;
    for (int n = wv; n < N; n += nw) {
        float wn = w[n];
        u16x4 hv = *reinterpret_cast<const u16x4*>(&ob[(size_t)n * 256 + lane * 4]);
        a0 = fmaf(wn, b2f((u16)hv[0]), a0);
        a1 = fmaf(wn, b2f((u16)hv[1]), a1);
        a2 = fmaf(wn, b2f((u16)hv[2]), a2);
        a3 = fmaf(wn, b2f((u16)hv[3]), a3);
    }
    sh[wid][lane * 4 + 0] = a0;
    sh[wid][lane * 4 + 1] = a1;
    sh[wid][lane * 4 + 2] = a2;
    sh[wid][lane * 4 + 3] = a3;
    __syncthreads();
    int t = threadIdx.x;
    float s = sh[0][t] + sh[1][t] + sh[2][t] + sh[3][t];
    atomicAdd(&pp[t], s);
}

__global__ void final_out(const float* __restrict__ pp, const float* __restrict__ W3,
                          const float* __restrict__ b3, int N, float* __restrict__ out) {
    __shared__ float acc[10];
    int t = threadIdx.x;  // 256
    if (t < 10) acc[t] = 0.f;
    __syncthreads();
    float pk = pp[t] / (float)N;
#pragma unroll
    for (int c = 0; c < 10; ++c) atomicAdd(&acc[c], pk * W3[t * 10 + c]);
    __syncthreads();
    if (t == 0) {
        float p[10];
        float mx = -INFINITY;
        for (int c = 0; c < 10; ++c) {
            p[c] = acc[c] + b3[c];
            mx = fmaxf(mx, p[c]);
        }
        float s = 0.f;
        for (int c = 0; c < 10; ++c) s += expf(p[c] - mx);
        float ls = logf(s);
        for (int c = 0; c < 10; ++c) out[c] = p[c] - mx - ls;
    }
}

extern "C" void kernel_launch(void* const* d_in, const int* in_sizes, int n_in,
                              void* d_out, int out_size, void* d_ws, size_t ws_size,
                              hipStream_t stream) {
    const float* x   = (const float*)d_in[0];
    const int*   ei  = (const int*)d_in[1];
    const float* W1  = (const float*)d_in[2];
    const float* as1 = (const float*)d_in[3];
    const float* ad1 = (const float*)d_in[4];
    const float* b1  = (const float*)d_in[5];
    const float* W2  = (const float*)d_in[6];
    const float* as2 = (const float*)d_in[7];
    const float* ad2 = (const float*)d_in[8];
    const float* b2  = (const float*)d_in[9];
    const float* W3  = (const float*)d_in[10];
    const float* as3 = (const float*)d_in[11];
    const float* ad3 = (const float*)d_in[12];
    const float* b3  = (const float*)d_in[13];
    float* out = (float*)d_out;

    const int N = in_sizes[0] / 128;   // 50000
    const int E = in_sizes[1] / 2;     // 800000
    const int Etot = E + N;
    const int NB = (N + 127) >> 7;     // 128-dst buckets
    const int* srcI = ei;
    const int* dstI = ei + E;

    char* base = (char*)d_ws;
    size_t off = 0;
    auto alloc = [&](size_t bytes) {
        void* p = base + off;
        off = (off + bytes + 255) & ~(size_t)255;
        return p;
    };
    u16* x_bf  = (u16*)alloc((size_t)N * 128 * 2);
    unsigned* h8 = (unsigned*)alloc((size_t)N * 256);
    u16* oa_bf = (u16*)alloc((size_t)N * 256 * 2);
    u16* ob_bf = (u16*)alloc((size_t)N * 256 * 2);
    u16* w1t   = (u16*)alloc(256 * 128 * 2);
    u16* w2t   = (u16*)alloc(256 * 256 * 2);
    float* pq   = (float*)alloc((size_t)N * 8 * 4);   // [n][4] float2
    float* al_d = (float*)alloc((size_t)N * 4 * 4);
    float* pq3  = (float*)alloc((size_t)N * 2 * 4);   // [n] float2
    // contiguous zero region: bcnt | wq | pp
    int* bcnt   = (int*)alloc(512 * 4);
    float* wq   = (float*)alloc((size_t)N * 4);
    float* pp   = (float*)alloc(256 * 4);
    int* rp     = (int*)alloc((size_t)(N + 1) * 4);
    int* bbase  = (int*)alloc(512 * 4);
    int* bcursor = (int*)alloc(512 * 4);
    unsigned* binned = (unsigned*)alloc((size_t)Etot * 4);
    u16* srcp   = (u16*)alloc((size_t)Etot * 2);

    // ---- prep: cast x, transpose weights, zero scratch (one dispatch) ----
    const int n4 = N * 128 / 4;
    const int B0 = (n4 + 255) / 256;
    const int B1 = B0 + (128 * 256 + 255) / 256;
    const int B2 = B1 + (256 * 256 + 255) / 256;
    int span = (int)(((char*)(pp + 256) - (char*)bcnt) / 4);
    const int B3 = B2 + (span + 255) / 256;
    prep<<<B3, 256, 0, stream>>>(x, x_bf, n4, W1, w1t, W2, w2t,
                                 bcnt, span, B0, B1, B2);

    // ---- bucketed CSR build ----
    bucket_hist<<<(Etot + 2047) / 2048, 256, 0, stream>>>(dstI, E, Etot, bcnt, NB);
    bucket_scan<<<1, 512, 0, stream>>>(bcnt, NB, Etot, bbase, bcursor, rp, N);
    bin_scatter<<<(Etot + 256 * EPB - 1) / (256 * EPB), 256, 0, stream>>>(
        srcI, dstI, E, Etot, bcursor, binned, NB);
    bucket_csr<<<NB, 256, 0, stream>>>(binned, bbase, N, rp, srcp);

    const int FUSED_BLOCKS = (N + 3) / 4;
    const int GX = (N + 127) / 128;

    // ---- layer 1: x_bf[N,128] -> oa_bf[N,256], ELU ----
    {
        dim3 g(GX, 2);
        gemm_mfma_fused<<<g, 256, 0, stream>>>(x_bf, w1t, N, 128, as1, ad1,
                                               (unsigned char*)h8, pq, al_d);
        gat_fused_h4<true><<<FUSED_BLOCKS, 256, 0, stream>>>(
            h8, pq, al_d, b1, rp, srcp, N, oa_bf);
    }
    // ---- layer 2: oa_bf -> ob_bf, ELU ----
    {
        dim3 g(GX, 2);
        gemm_mfma_fused<<<g, 256, 0, stream>>>(oa_bf, w2t, N, 256, as2, ad2,
                                               (unsigned char*)h8, pq, al_d);
        gat_fused_h4<true><<<FUSED_BLOCKS, 256, 0, stream>>>(
            h8, pq, al_d, b2, rp, srcp, N, ob_bf);
    }
    // ---- layer 3 (linear-collapsed): pooled = (1/N * sum_s w_s ob_s) @ W3 + b3
    {
        compute_al3<<<(N + 3) / 4, 256, 0, stream>>>(ob_bf, W3, as3, ad3, N, pq3, al_d);
        l3_edge<<<(N + 3) / 4, 256, 0, stream>>>(pq3, al_d, rp, srcp, N, wq);
        wcolsum<<<1024, 256, 0, stream>>>(ob_bf, wq, N, pp);
        final_out<<<1, 256, 0, stream>>>(pp, W3, b3, N, out);
    }
}